// Round 10
// baseline (210.021 us; speedup 1.0000x reference)
//
#include <hip/hip_runtime.h>
#include <math.h>

typedef __attribute__((ext_vector_type(4))) float f32x4;
typedef __attribute__((ext_vector_type(16))) float f32x16;
typedef __attribute__((ext_vector_type(8))) short short8;

#define DI __device__ __forceinline__

static constexpr int Bb = 8;
static constexpr int Nn = 1024;
static constexpr int Dd = 256;

DI unsigned short f2bf(float f) {
  union { float f; unsigned u; } v; v.f = f;
  unsigned r = v.u + 0x7fffu + ((v.u >> 16) & 1u);
  return (unsigned short)(r >> 16);
}
DI float bf2f(unsigned short h) {
  union { unsigned u; float f; } v; v.u = ((unsigned)h) << 16; return v.f;
}

DI void gload_lds16(const void* g, void* l) {
  __builtin_amdgcn_global_load_lds((const __attribute__((address_space(1))) unsigned int*)g,
                                   (__attribute__((address_space(3))) unsigned int*)l, 16, 0, 0);
}

// ---------------- stats over sequence dim (axis=1) ----------------
__global__ void stats_pass1(const float* __restrict__ x, float* __restrict__ partial) {
  int d = threadIdx.x;
  int b = blockIdx.x >> 5;
  int c = blockIdx.x & 31;
  const float* p = x + ((size_t)b * Nn + c * 32) * Dd + d;
  float s = 0.f, ss = 0.f;
  for (int i = 0; i < 32; i++) { float v = p[(size_t)i * Dd]; s += v; ss += v * v; }
  float* o = partial + ((size_t)(b * 32 + c) * 2) * Dd + d;
  o[0] = s; o[Dd] = ss;
}

__global__ void stats_pass2(const float* __restrict__ partial, float* __restrict__ mean,
                            float* __restrict__ rstd) {
  int d = threadIdx.x; int b = blockIdx.x;
  float s = 0.f, ss = 0.f;
  for (int c = 0; c < 32; c++) {
    s  += partial[((size_t)(b * 32 + c) * 2) * Dd + d];
    ss += partial[((size_t)(b * 32 + c) * 2) * Dd + Dd + d];
  }
  float m = s * (1.f / Nn);
  float var = ss * (1.f / Nn) - m * m;
  mean[b * Dd + d] = m;
  rstd[b * Dd + d] = rsqrtf(var + 1e-5f);
}

// ---------------- norm (+pos) + swish -> bf16 ----------------
template<bool POS>
__global__ void norm_swish(const float* __restrict__ x, const float* __restrict__ mean,
                           const float* __restrict__ rstd, const float* __restrict__ gamma,
                           const float* __restrict__ beta, const float* __restrict__ pos,
                           unsigned short* __restrict__ out) {
  size_t idx = ((size_t)blockIdx.x * 256 + threadIdx.x) * 4;
  int d = (int)(idx & (Dd - 1));
  size_t row = idx >> 8;
  int b = (int)(row >> 10);
  int n = (int)(row & (Nn - 1));
  const float4 xv = *(const float4*)(x + idx);
  const float4 gv = *(const float4*)(gamma + d);
  const float4 bv = *(const float4*)(beta + d);
  const float4 mv = *(const float4*)(mean + b * Dd + d);
  const float4 rv = *(const float4*)(rstd + b * Dd + d);
  float v[4]  = {xv.x, xv.y, xv.z, xv.w};
  float g[4]  = {gv.x, gv.y, gv.z, gv.w};
  float be[4] = {bv.x, bv.y, bv.z, bv.w};
  float mm[4] = {mv.x, mv.y, mv.z, mv.w};
  float rr[4] = {rv.x, rv.y, rv.z, rv.w};
  float pp[4] = {0.f, 0.f, 0.f, 0.f};
  if (POS) {
    const float4 pv = *(const float4*)(pos + (size_t)n * Dd + d);
    pp[0] = pv.x; pp[1] = pv.y; pp[2] = pv.z; pp[3] = pv.w;
  }
  ushort4 o;
  unsigned short* op = (unsigned short*)&o;
  #pragma unroll
  for (int j = 0; j < 4; j++) {
    float val = (v[j] - mm[j]) * rr[j] * g[j] + be[j];
    if (POS) val += pp[j];
    float sw = val / (1.f + __expf(-val));
    op[j] = f2bf(sw);
  }
  *(ushort4*)(out + idx) = o;
}

// ---------------- time projection ----------------
__global__ void time_proj(const float* __restrict__ t, const float* __restrict__ Wt,
                          const float* __restrict__ bt, float* __restrict__ sig_ts) {
  int j = blockIdx.x * 256 + threadIdx.x;
  int b = blockIdx.y;
  const float* tb = t + b * 256;
  float acc = bt[256 + j];
  for (int k = 0; k < 256; k++) acc += tb[k] * Wt[k * 1280 + 256 + j];
  sig_ts[b * 1024 + j] = 1.f / (1.f + __expf(-acc));
}

// ---------------- weight transpose f32 [R][C] -> bf16 [C][R] ----------------
__global__ void transpose_w(const float* __restrict__ in, unsigned short* __restrict__ out,
                            int R, int C) {
  __shared__ float tile[32][33];
  int c0 = blockIdx.x * 32, r0 = blockIdx.y * 32;
  int tx = threadIdx.x & 31, ty = threadIdx.x >> 5;
  for (int i = ty; i < 32; i += 8)
    tile[i][tx] = in[(size_t)(r0 + i) * C + c0 + tx];
  __syncthreads();
  for (int i = ty; i < 32; i += 8)
    out[(size_t)(c0 + i) * R + r0 + tx] = f2bf(tile[tx][i]);
}

// ---------------- q2/k2 precompute from qk buffer ----------------
// qk: bf16 [8192][1024]; q2,k2: f32 [64][1024] (bh-major)
__global__ void q2k2_kernel(const unsigned short* __restrict__ qk,
                            float* __restrict__ q2, float* __restrict__ k2) {
  const int wave = threadIdx.x >> 6, lane = threadIdx.x & 63;
  const int r = blockIdx.x * 4 + wave;   // row 0..8191
  const int b = r >> 10, n = r & 1023;
  short8 v = *(const short8*)(qk + (size_t)r * 1024 + lane * 16);
  float s = 0.f;
  #pragma unroll
  for (int j = 0; j < 8; j++) { float f = bf2f(((unsigned short*)&v)[j]); s += f * f; }
  short8 v2 = *(const short8*)(qk + (size_t)r * 1024 + lane * 16 + 8);
  #pragma unroll
  for (int j = 0; j < 8; j++) { float f = bf2f(((unsigned short*)&v2)[j]); s += f * f; }
  s += __shfl_xor(s, 1);
  s += __shfl_xor(s, 2);
  if ((lane & 3) == 0) {
    const int seg = lane >> 2;                 // 0..15
    float* dst = (seg < 8) ? q2 : k2;
    dst[(size_t)(b * 8 + (seg & 7)) * 1024 + n] = s;
  }
}

// ---------------- GEMM (m97-style: linear LDS + global_load_lds) ----------------
// EPI 0: qkv split epilogue; EPI 1: f32 out = acc+bias+res; EPI 2: gated swish -> bf16
template<int EPI, int BN>
__global__ __launch_bounds__(256, 3) void gemm2(
    const unsigned short* __restrict__ A, const unsigned short* __restrict__ BT,
    const float* __restrict__ bias, const float* __restrict__ res,
    const float* __restrict__ aux, unsigned short* __restrict__ obf,
    float* __restrict__ of, unsigned short* __restrict__ vtb, int K, int Ndim) {
  __shared__ __align__(16) unsigned short As[128 * 64];
  __shared__ __align__(16) unsigned short Bs[BN * 64];
  const int tid = threadIdx.x, lane = tid & 63, wave = tid >> 6;
  const int wr = wave >> 1, wc = wave & 1;
  constexpr int NI = (BN == 128) ? 4 : 2;
  constexpr int WCW = (BN == 128) ? 64 : 32;
  const int m0 = blockIdx.y * 128, n0 = blockIdx.x * BN;
  f32x4 acc[4][NI] = {};
  for (int k0 = 0; k0 < K; k0 += 64) {
    __syncthreads();
    #pragma unroll
    for (int p = 0; p < 4; p++) {
      const int o = p * 4096 + tid * 16;
      const int row = o >> 7, c8 = (o >> 4) & 7;
      gload_lds16(A + (size_t)(m0 + row) * K + k0 + c8 * 8, (char*)As + o);
    }
    #pragma unroll
    for (int p = 0; p < BN / 32; p++) {
      const int o = p * 4096 + tid * 16;
      const int row = o >> 7, c8 = (o >> 4) & 7;
      gload_lds16(BT + (size_t)(n0 + row) * K + k0 + c8 * 8, (char*)Bs + o);
    }
    __syncthreads();
    #pragma unroll
    for (int ks = 0; ks < 2; ks++) {
      short8 af[4], bfr[NI];
      #pragma unroll
      for (int i = 0; i < 4; i++)
        af[i] = *(const short8*)&As[(wr * 64 + i * 16 + (lane & 15)) * 64 + ks * 32 + (lane >> 4) * 8];
      #pragma unroll
      for (int i = 0; i < NI; i++)
        bfr[i] = *(const short8*)&Bs[(wc * WCW + i * 16 + (lane & 15)) * 64 + ks * 32 + (lane >> 4) * 8];
      #pragma unroll
      for (int mi = 0; mi < 4; mi++)
        #pragma unroll
        for (int ni = 0; ni < NI; ni++)
          acc[mi][ni] = __builtin_amdgcn_mfma_f32_16x16x32_bf16(af[mi], bfr[ni], acc[mi][ni], 0, 0, 0);
    }
  }
  const int rbase = m0 + wr * 64 + ((lane >> 4) << 2);
  const int cb = n0 + wc * WCW + (lane & 15);
  #pragma unroll
  for (int mi = 0; mi < 4; mi++) {
    #pragma unroll
    for (int ni = 0; ni < NI; ni++) {
      const int col = cb + ni * 16;
      const float bv = bias[col];
      const int r0_ = rbase + mi * 16;
      if (EPI == 0) {
        if (col < 1024) {
          #pragma unroll
          for (int j = 0; j < 4; j++)
            obf[(size_t)(r0_ + j) * 1024 + col] = f2bf(acc[mi][ni][j] + bv);
        } else {
          const int hh = (col - 1024) >> 8, cc = (col - 1024) & 255;
          const int b_ = r0_ >> 10, nb = r0_ & (Nn - 1);
          ushort4 pk;
          unsigned short* pp = (unsigned short*)&pk;
          #pragma unroll
          for (int j = 0; j < 4; j++) pp[j] = f2bf(acc[mi][ni][j] + bv);
          *(ushort4*)&vtb[((size_t)((b_ * 8 + hh) * 256 + cc)) * 1024 + nb] = pk;
        }
      } else if (EPI == 1) {
        #pragma unroll
        for (int j = 0; j < 4; j++) {
          size_t o = (size_t)(r0_ + j) * Ndim + col;
          of[o] = acc[mi][ni][j] + bv + res[o];
        }
      } else {
        const int b_ = r0_ >> 10;
        const float sg = aux[b_ * 1024 + col];
        #pragma unroll
        for (int j = 0; j < 4; j++) {
          float g = (acc[mi][ni][j] + bv) * sg;
          obf[(size_t)(r0_ + j) * Ndim + col] = f2bf(g / (1.f + __expf(-g)));
        }
      }
    }
  }
}

// ---------------- Gaussian-kernel attention v3 (round-6 PROVEN source) ----------------
// ONLY delta vs round 6: s_setprio(1/0) around the two MFMA clusters (T5; pure
// scheduler hint, zero semantic effect). k2 stays a GLOBAL read: staging k2 via
// ds_write while global_load_lds is in flight broke correctness (round 9).
__global__ __launch_bounds__(512, 2) void attn3(
    const unsigned short* __restrict__ qk, const unsigned short* __restrict__ vt,
    const float* __restrict__ q2g, const float* __restrict__ k2g,
    unsigned short* __restrict__ aout, const float* __restrict__ scale_p) {
  const int dd = blockIdx.x;
  const int bh = (dd & 7) + ((dd >> 5) << 3);   // 4 q-tiles of one bh -> same XCD
  const int qt = (dd >> 3) & 3;
  const int b = bh >> 3, h = bh & 7;
  const float sc = scale_p[0];
  const float inv_s2 = 1.f / (sc * sc);

  __shared__ __align__(16) unsigned short Ks[2][64 * 64];
  __shared__ __align__(16) unsigned short Vs[2][256 * 64];

  const int tid = threadIdx.x, lane = tid & 63, wave = tid >> 6;
  const int l31 = lane & 31, lh = lane >> 5;
  const int qr0 = qt * 256 + wave * 32;

  auto stage = [&](int kt, int buf) {
    { // K tile 8 KiB (inverse-swizzled global source, linear LDS dest)
      const int row = tid >> 3;
      const int c8 = (tid & 7) ^ (row & 7);
      gload_lds16(qk + (size_t)(b * 1024 + kt * 64 + row) * 1024 + 512 + h * 64 + c8 * 8,
                  (char*)&Ks[buf][0] + tid * 16);
    }
    #pragma unroll
    for (int p = 0; p < 4; p++) { // V tile 32 KiB
      const int o = p * 8192 + tid * 16;
      const int row = o >> 7;
      const int c8 = ((o >> 4) & 7) ^ (row & 7);
      gload_lds16(vt + (size_t)(bh * 256 + row) * 1024 + kt * 64 + c8 * 8,
                  (char*)&Vs[buf][0] + o);
    }
  };

  stage(0, 0);

  // Q B-frags + q2, direct from global (once per block)
  short8 qfrag[4];
  const unsigned short* qbase = qk + (size_t)(b * 1024 + qr0 + l31) * 1024 + h * 64;
  #pragma unroll
  for (int ks = 0; ks < 4; ks++)
    qfrag[ks] = *(const short8*)(qbase + ks * 16 + lh * 8);
  const float q2v = q2g[(size_t)bh * 1024 + qr0 + l31];

  f32x16 acc[8] = {};
  __syncthreads();   // prologue stage visible

  for (int kt = 0; kt < 16; kt++) {
    const int cur = kt & 1;
    if (kt < 15) stage(kt + 1, cur ^ 1);   // in flight until the barrier

    uint4 pa[4];   // P A-frags, [k-16-slice] x 4 words
    #pragma unroll
    for (int mi = 0; mi < 2; mi++) {
      // S^T = mfma(K, Q): D[k_local][q], k rows mi*32..+31 of this tile
      f32x16 sacc = {};
      __builtin_amdgcn_s_setprio(1);
      #pragma unroll
      for (int ks = 0; ks < 4; ks++) {
        const int row = mi * 32 + l31;
        const int sl = (ks * 2 + lh) ^ (row & 7);
        short8 kf = *(const short8*)((const char*)&Ks[cur][0] + row * 128 + sl * 16);
        sacc = __builtin_amdgcn_mfma_f32_32x32x16_bf16(kf, qfrag[ks], sacc, 0, 0, 0);
      }
      __builtin_amdgcn_s_setprio(0);
      // d2 -> exp, all registers; k2 via broadcast global float4
      const float* k2p = k2g + (size_t)bh * 1024 + kt * 64 + mi * 32 + lh * 4;
      float pr[16];
      #pragma unroll
      for (int g = 0; g < 4; g++) {
        const float4 k2v = *(const float4*)(k2p + g * 8);
        #pragma unroll
        for (int j = 0; j < 4; j++) {
          float d2 = q2v + ((const float*)&k2v)[j] - 2.f * sacc[g * 4 + j];
          pr[g * 4 + j] = __expf(-fmaxf(d2, 0.f) * inv_s2);
        }
      }
      // pack to bf16 A-frags: 8 cvt_pk + 4 permlane32_swap per mi.
      // permlane32_swap(w0,w2): w0'={w0.lo,w2.lo}=word0, w2'={w0.hi,w2.hi}=word2.
      #pragma unroll
      for (int ksh = 0; ksh < 2; ksh++) {
        unsigned w0, w1, w2, w3;
        const int o = ksh * 8;
        asm("v_cvt_pk_bf16_f32 %0, %1, %2" : "=v"(w0) : "v"(pr[o + 0]), "v"(pr[o + 1]));
        asm("v_cvt_pk_bf16_f32 %0, %1, %2" : "=v"(w1) : "v"(pr[o + 2]), "v"(pr[o + 3]));
        asm("v_cvt_pk_bf16_f32 %0, %1, %2" : "=v"(w2) : "v"(pr[o + 4]), "v"(pr[o + 5]));
        asm("v_cvt_pk_bf16_f32 %0, %1, %2" : "=v"(w3) : "v"(pr[o + 6]), "v"(pr[o + 7]));
        asm("v_permlane32_swap_b32 %0, %1" : "+v"(w0), "+v"(w2));
        asm("v_permlane32_swap_b32 %0, %1" : "+v"(w1), "+v"(w3));
        pa[mi * 2 + ksh] = make_uint4(w0, w1, w2, w3);
      }
    }
    // PV: acc[ci] += P(32q x 64k) @ V(64k x 256c), V from swizzled LDS
    __builtin_amdgcn_s_setprio(1);
    #pragma unroll
    for (int ci = 0; ci < 8; ci++) {
      #pragma unroll
      for (int ks = 0; ks < 4; ks++) {
        const int row = ci * 32 + l31;
        const int sl = (ks * 2 + lh) ^ (row & 7);
        short8 vf = *(const short8*)((const char*)&Vs[cur][0] + row * 128 + sl * 16);
        short8 paf = *(const short8*)&pa[ks];
        acc[ci] = __builtin_amdgcn_mfma_f32_32x32x16_bf16(paf, vf, acc[ci], 0, 0, 0);
      }
    }
    __builtin_amdgcn_s_setprio(0);
    __syncthreads();   // cur reads done; stage(kt+1) drained (vmcnt0 at barrier)
  }

  const size_t row0 = (size_t)(b * 1024 + qr0);
  #pragma unroll
  for (int ci = 0; ci < 8; ci++) {
    #pragma unroll
    for (int r = 0; r < 16; r++) {
      const int q = (r & 3) + 8 * (r >> 2) + 4 * lh;
      aout[(row0 + q) * 2048 + h * 256 + ci * 32 + l31] = f2bf(acc[ci][r]);
    }
  }
}

extern "C" void kernel_launch(void* const* d_in, const int* in_sizes, int n_in,
                              void* d_out, int out_size, void* d_ws, size_t ws_size,
                              hipStream_t stream) {
  (void)in_sizes; (void)n_in; (void)out_size; (void)ws_size;
  const float* x      = (const float*)d_in[0];
  const float* t      = (const float*)d_in[1];
  const float* gamma  = (const float*)d_in[2];
  const float* beta   = (const float*)d_in[3];
  const float* pos    = (const float*)d_in[4];
  const float* Wqkv   = (const float*)d_in[5];
  const float* bqkv   = (const float*)d_in[6];
  const float* Wm     = (const float*)d_in[7];
  const float* bm     = (const float*)d_in[8];
  const float* Wt     = (const float*)d_in[9];
  const float* bt     = (const float*)d_in[10];
  const float* gamma1 = (const float*)d_in[11];
  const float* beta1  = (const float*)d_in[12];
  const float* Wf1    = (const float*)d_in[13];
  const float* bf1    = (const float*)d_in[14];
  const float* Wf2    = (const float*)d_in[15];
  const float* bf2    = (const float*)d_in[16];
  const float* scale  = (const float*)d_in[17];
  float* out = (float*)d_out;

  char* ws = (char*)d_ws;
  size_t off = 0;
  auto alloc = [&](size_t bytes) -> void* {
    void* p = ws + off;
    off += (bytes + 255) & ~(size_t)255;
    return p;
  };
  unsigned short* qkb   = (unsigned short*)alloc((size_t)8192 * 1024 * 2);
  unsigned short* vtb   = (unsigned short*)alloc((size_t)64 * 256 * 1024 * 2);
  unsigned short* aoutb = (unsigned short*)alloc((size_t)8192 * 2048 * 2);
  unsigned short* hbuf  = (unsigned short*)alloc((size_t)8192 * 256 * 2);
  unsigned short* ffbuf = (unsigned short*)alloc((size_t)8192 * 1024 * 2);
  float* x1             = (float*)alloc((size_t)8192 * 256 * 4);
  unsigned short* WqkvT = (unsigned short*)alloc((size_t)3072 * 256 * 2);
  unsigned short* WmT   = (unsigned short*)alloc((size_t)256 * 2048 * 2);
  unsigned short* Wf1T  = (unsigned short*)alloc((size_t)1024 * 256 * 2);
  unsigned short* Wf2T  = (unsigned short*)alloc((size_t)256 * 1024 * 2);
  float* partial = (float*)alloc((size_t)8 * 32 * 2 * 256 * 4);
  float* mean1   = (float*)alloc(8 * 256 * 4);
  float* rstd1   = (float*)alloc(8 * 256 * 4);
  float* mean2   = (float*)alloc(8 * 256 * 4);
  float* rstd2   = (float*)alloc(8 * 256 * 4);
  float* sig_ts  = (float*)alloc(8 * 1024 * 4);
  float* q2g     = (float*)alloc((size_t)64 * 1024 * 4);
  float* k2g     = (float*)alloc((size_t)64 * 1024 * 4);

  transpose_w<<<dim3(96, 8),  256, 0, stream>>>(Wqkv, WqkvT, 256, 3072);
  transpose_w<<<dim3(8, 64),  256, 0, stream>>>(Wm,   WmT,   2048, 256);
  transpose_w<<<dim3(32, 8),  256, 0, stream>>>(Wf1,  Wf1T,  256, 1024);
  transpose_w<<<dim3(8, 32),  256, 0, stream>>>(Wf2,  Wf2T,  1024, 256);

  stats_pass1<<<256, 256, 0, stream>>>(x, partial);
  stats_pass2<<<8, 256, 0, stream>>>(partial, mean1, rstd1);
  time_proj<<<dim3(4, 8), 256, 0, stream>>>(t, Wt, bt, sig_ts);
  norm_swish<true><<<2048, 256, 0, stream>>>(x, mean1, rstd1, gamma, beta, pos, hbuf);

  gemm2<0, 128><<<dim3(24, 64), 256, 0, stream>>>(hbuf, WqkvT, bqkv, nullptr, nullptr,
                                                  qkb, nullptr, vtb, 256, 3072);
  q2k2_kernel<<<2048, 256, 0, stream>>>(qkb, q2g, k2g);
  attn3<<<256, 512, 0, stream>>>(qkb, vtb, q2g, k2g, aoutb, scale);
  gemm2<1, 64><<<dim3(4, 64), 256, 0, stream>>>(aoutb, WmT, bm, x, nullptr,
                                                nullptr, x1, nullptr, 2048, 256);

  stats_pass1<<<256, 256, 0, stream>>>(x1, partial);
  stats_pass2<<<8, 256, 0, stream>>>(partial, mean2, rstd2);
  norm_swish<false><<<2048, 256, 0, stream>>>(x1, mean2, rstd2, gamma1, beta1, nullptr, hbuf);

  gemm2<2, 128><<<dim3(8, 64), 256, 0, stream>>>(hbuf, Wf1T, bf1, nullptr, sig_ts,
                                                 ffbuf, nullptr, nullptr, 256, 1024);
  gemm2<1, 64><<<dim3(4, 64), 256, 0, stream>>>(ffbuf, Wf2T, bf2, x1, nullptr,
                                                nullptr, out, nullptr, 1024, 256);
}

// Round 12
// 203.191 us; speedup vs baseline: 1.0336x; 1.0336x over previous
//
#include <hip/hip_runtime.h>
#include <math.h>

typedef __attribute__((ext_vector_type(4))) float f32x4;
typedef __attribute__((ext_vector_type(16))) float f32x16;
typedef __attribute__((ext_vector_type(8))) short short8;

#define DI __device__ __forceinline__

static constexpr int Bb = 8;
static constexpr int Nn = 1024;
static constexpr int Dd = 256;

DI unsigned short f2bf(float f) {
  union { float f; unsigned u; } v; v.f = f;
  unsigned r = v.u + 0x7fffu + ((v.u >> 16) & 1u);
  return (unsigned short)(r >> 16);
}
DI float bf2f(unsigned short h) {
  union { unsigned u; float f; } v; v.u = ((unsigned)h) << 16; return v.f;
}

DI void gload_lds16(const void* g, void* l) {
  __builtin_amdgcn_global_load_lds((const __attribute__((address_space(1))) unsigned int*)g,
                                   (__attribute__((address_space(3))) unsigned int*)l, 16, 0, 0);
}

// ---------------- stats over sequence dim (axis=1) ----------------
__global__ void stats_pass1(const float* __restrict__ x, float* __restrict__ partial) {
  int d = threadIdx.x;
  int b = blockIdx.x >> 5;
  int c = blockIdx.x & 31;
  const float* p = x + ((size_t)b * Nn + c * 32) * Dd + d;
  float s = 0.f, ss = 0.f;
  for (int i = 0; i < 32; i++) { float v = p[(size_t)i * Dd]; s += v; ss += v * v; }
  float* o = partial + ((size_t)(b * 32 + c) * 2) * Dd + d;
  o[0] = s; o[Dd] = ss;
}

__global__ void stats_pass2(const float* __restrict__ partial, float* __restrict__ mean,
                            float* __restrict__ rstd) {
  int d = threadIdx.x; int b = blockIdx.x;
  float s = 0.f, ss = 0.f;
  for (int c = 0; c < 32; c++) {
    s  += partial[((size_t)(b * 32 + c) * 2) * Dd + d];
    ss += partial[((size_t)(b * 32 + c) * 2) * Dd + Dd + d];
  }
  float m = s * (1.f / Nn);
  float var = ss * (1.f / Nn) - m * m;
  mean[b * Dd + d] = m;
  rstd[b * Dd + d] = rsqrtf(var + 1e-5f);
}

// ---------------- norm (+pos) + swish -> bf16 ----------------
template<bool POS>
__global__ void norm_swish(const float* __restrict__ x, const float* __restrict__ mean,
                           const float* __restrict__ rstd, const float* __restrict__ gamma,
                           const float* __restrict__ beta, const float* __restrict__ pos,
                           unsigned short* __restrict__ out) {
  size_t idx = ((size_t)blockIdx.x * 256 + threadIdx.x) * 4;
  int d = (int)(idx & (Dd - 1));
  size_t row = idx >> 8;
  int b = (int)(row >> 10);
  int n = (int)(row & (Nn - 1));
  const float4 xv = *(const float4*)(x + idx);
  const float4 gv = *(const float4*)(gamma + d);
  const float4 bv = *(const float4*)(beta + d);
  const float4 mv = *(const float4*)(mean + b * Dd + d);
  const float4 rv = *(const float4*)(rstd + b * Dd + d);
  float v[4]  = {xv.x, xv.y, xv.z, xv.w};
  float g[4]  = {gv.x, gv.y, gv.z, gv.w};
  float be[4] = {bv.x, bv.y, bv.z, bv.w};
  float mm[4] = {mv.x, mv.y, mv.z, mv.w};
  float rr[4] = {rv.x, rv.y, rv.z, rv.w};
  float pp[4] = {0.f, 0.f, 0.f, 0.f};
  if (POS) {
    const float4 pv = *(const float4*)(pos + (size_t)n * Dd + d);
    pp[0] = pv.x; pp[1] = pv.y; pp[2] = pv.z; pp[3] = pv.w;
  }
  ushort4 o;
  unsigned short* op = (unsigned short*)&o;
  #pragma unroll
  for (int j = 0; j < 4; j++) {
    float val = (v[j] - mm[j]) * rr[j] * g[j] + be[j];
    if (POS) val += pp[j];
    float sw = val / (1.f + __expf(-val));
    op[j] = f2bf(sw);
  }
  *(ushort4*)(out + idx) = o;
}

// ---------------- time projection ----------------
__global__ void time_proj(const float* __restrict__ t, const float* __restrict__ Wt,
                          const float* __restrict__ bt, float* __restrict__ sig_ts) {
  int j = blockIdx.x * 256 + threadIdx.x;
  int b = blockIdx.y;
  const float* tb = t + b * 256;
  float acc = bt[256 + j];
  for (int k = 0; k < 256; k++) acc += tb[k] * Wt[k * 1280 + 256 + j];
  sig_ts[b * 1024 + j] = 1.f / (1.f + __expf(-acc));
}

// ---------------- weight transpose f32 [R][C] -> bf16 [C][R] ----------------
__global__ void transpose_w(const float* __restrict__ in, unsigned short* __restrict__ out,
                            int R, int C) {
  __shared__ float tile[32][33];
  int c0 = blockIdx.x * 32, r0 = blockIdx.y * 32;
  int tx = threadIdx.x & 31, ty = threadIdx.x >> 5;
  for (int i = ty; i < 32; i += 8)
    tile[i][tx] = in[(size_t)(r0 + i) * C + c0 + tx];
  __syncthreads();
  for (int i = ty; i < 32; i += 8)
    out[(size_t)(c0 + i) * R + r0 + tx] = f2bf(tile[tx][i]);
}

// ---------------- q2/k2 precompute from qk buffer ----------------
// qk: bf16 [8192][1024]; q2,k2: f32 [64][1024] (bh-major)
__global__ void q2k2_kernel(const unsigned short* __restrict__ qk,
                            float* __restrict__ q2, float* __restrict__ k2) {
  const int wave = threadIdx.x >> 6, lane = threadIdx.x & 63;
  const int r = blockIdx.x * 4 + wave;   // row 0..8191
  const int b = r >> 10, n = r & 1023;
  short8 v = *(const short8*)(qk + (size_t)r * 1024 + lane * 16);
  float s = 0.f;
  #pragma unroll
  for (int j = 0; j < 8; j++) { float f = bf2f(((unsigned short*)&v)[j]); s += f * f; }
  short8 v2 = *(const short8*)(qk + (size_t)r * 1024 + lane * 16 + 8);
  #pragma unroll
  for (int j = 0; j < 8; j++) { float f = bf2f(((unsigned short*)&v2)[j]); s += f * f; }
  s += __shfl_xor(s, 1);
  s += __shfl_xor(s, 2);
  if ((lane & 3) == 0) {
    const int seg = lane >> 2;                 // 0..15
    float* dst = (seg < 8) ? q2 : k2;
    dst[(size_t)(b * 8 + (seg & 7)) * 1024 + n] = s;
  }
}

// ---------------- GEMM (m97-style: linear LDS + global_load_lds) ----------------
// T1 XCD swizzle (ONLY delta vs round-6 gemm2): bijective remap so the blocks
// sharing an A-panel co-reside on one XCD; A re-reads become L2 hits.
// EPI 0: qkv split epilogue; EPI 1: f32 out = acc+bias+res; EPI 2: gated swish -> bf16
template<int EPI, int BN>
__global__ __launch_bounds__(256, 3) void gemm2(
    const unsigned short* __restrict__ A, const unsigned short* __restrict__ BT,
    const float* __restrict__ bias, const float* __restrict__ res,
    const float* __restrict__ aux, unsigned short* __restrict__ obf,
    float* __restrict__ of, unsigned short* __restrict__ vtb, int K, int Ndim) {
  __shared__ __align__(16) unsigned short As[128 * 64];
  __shared__ __align__(16) unsigned short Bs[BN * 64];
  const int tid = threadIdx.x, lane = tid & 63, wave = tid >> 6;
  const int wr = wave >> 1, wc = wave & 1;
  constexpr int NI = (BN == 128) ? 4 : 2;
  constexpr int WCW = (BN == 128) ? 64 : 32;
  const int nwg = gridDim.x * gridDim.y;
  const int orig = blockIdx.y * gridDim.x + blockIdx.x;
  const int swz = (orig & 7) * (nwg >> 3) + (orig >> 3);
  const int m0 = (swz / gridDim.x) * 128, n0 = (swz % gridDim.x) * BN;
  f32x4 acc[4][NI] = {};
  for (int k0 = 0; k0 < K; k0 += 64) {
    __syncthreads();
    #pragma unroll
    for (int p = 0; p < 4; p++) {
      const int o = p * 4096 + tid * 16;
      const int row = o >> 7, c8 = (o >> 4) & 7;
      gload_lds16(A + (size_t)(m0 + row) * K + k0 + c8 * 8, (char*)As + o);
    }
    #pragma unroll
    for (int p = 0; p < BN / 32; p++) {
      const int o = p * 4096 + tid * 16;
      const int row = o >> 7, c8 = (o >> 4) & 7;
      gload_lds16(BT + (size_t)(n0 + row) * K + k0 + c8 * 8, (char*)Bs + o);
    }
    __syncthreads();
    #pragma unroll
    for (int ks = 0; ks < 2; ks++) {
      short8 af[4], bfr[NI];
      #pragma unroll
      for (int i = 0; i < 4; i++)
        af[i] = *(const short8*)&As[(wr * 64 + i * 16 + (lane & 15)) * 64 + ks * 32 + (lane >> 4) * 8];
      #pragma unroll
      for (int i = 0; i < NI; i++)
        bfr[i] = *(const short8*)&Bs[(wc * WCW + i * 16 + (lane & 15)) * 64 + ks * 32 + (lane >> 4) * 8];
      #pragma unroll
      for (int mi = 0; mi < 4; mi++)
        #pragma unroll
        for (int ni = 0; ni < NI; ni++)
          acc[mi][ni] = __builtin_amdgcn_mfma_f32_16x16x32_bf16(af[mi], bfr[ni], acc[mi][ni], 0, 0, 0);
    }
  }
  const int rbase = m0 + wr * 64 + ((lane >> 4) << 2);
  const int cb = n0 + wc * WCW + (lane & 15);
  #pragma unroll
  for (int mi = 0; mi < 4; mi++) {
    #pragma unroll
    for (int ni = 0; ni < NI; ni++) {
      const int col = cb + ni * 16;
      const float bv = bias[col];
      const int r0_ = rbase + mi * 16;
      if (EPI == 0) {
        if (col < 1024) {
          #pragma unroll
          for (int j = 0; j < 4; j++)
            obf[(size_t)(r0_ + j) * 1024 + col] = f2bf(acc[mi][ni][j] + bv);
        } else {
          const int hh = (col - 1024) >> 8, cc = (col - 1024) & 255;
          const int b_ = r0_ >> 10, nb = r0_ & (Nn - 1);
          ushort4 pk;
          unsigned short* pp = (unsigned short*)&pk;
          #pragma unroll
          for (int j = 0; j < 4; j++) pp[j] = f2bf(acc[mi][ni][j] + bv);
          *(ushort4*)&vtb[((size_t)((b_ * 8 + hh) * 256 + cc)) * 1024 + nb] = pk;
        }
      } else if (EPI == 1) {
        #pragma unroll
        for (int j = 0; j < 4; j++) {
          size_t o = (size_t)(r0_ + j) * Ndim + col;
          of[o] = acc[mi][ni][j] + bv + res[o];
        }
      } else {
        const int b_ = r0_ >> 10;
        const float sg = aux[b_ * 1024 + col];
        #pragma unroll
        for (int j = 0; j < 4; j++) {
          float g = (acc[mi][ni][j] + bv) * sg;
          obf[(size_t)(r0_ + j) * Ndim + col] = f2bf(g / (1.f + __expf(-g)));
        }
      }
    }
  }
}

// ---------------- Gaussian-kernel attention v3 (round-6 PROVEN source, verbatim) ----------------
// 8 waves x 32 q-rows each; P stays in registers (cvt_pk + permlane32_swap);
// q2/k2 precomputed; 1 barrier/iter; K/V double-buffered via global_load_lds.
// qk: bf16 [8192][1024]; vt: bf16 [bh][256][1024]; q2g/k2g: f32 [64][1024]
__global__ __launch_bounds__(512, 2) void attn3(
    const unsigned short* __restrict__ qk, const unsigned short* __restrict__ vt,
    const float* __restrict__ q2g, const float* __restrict__ k2g,
    unsigned short* __restrict__ aout, const float* __restrict__ scale_p) {
  const int dd = blockIdx.x;
  const int bh = (dd & 7) + ((dd >> 5) << 3);   // 4 q-tiles of one bh -> same XCD
  const int qt = (dd >> 3) & 3;
  const int b = bh >> 3, h = bh & 7;
  const float sc = scale_p[0];
  const float inv_s2 = 1.f / (sc * sc);

  __shared__ __align__(16) unsigned short Ks[2][64 * 64];
  __shared__ __align__(16) unsigned short Vs[2][256 * 64];

  const int tid = threadIdx.x, lane = tid & 63, wave = tid >> 6;
  const int l31 = lane & 31, lh = lane >> 5;
  const int qr0 = qt * 256 + wave * 32;

  auto stage = [&](int kt, int buf) {
    { // K tile 8 KiB (inverse-swizzled global source, linear LDS dest)
      const int row = tid >> 3;
      const int c8 = (tid & 7) ^ (row & 7);
      gload_lds16(qk + (size_t)(b * 1024 + kt * 64 + row) * 1024 + 512 + h * 64 + c8 * 8,
                  (char*)&Ks[buf][0] + tid * 16);
    }
    #pragma unroll
    for (int p = 0; p < 4; p++) { // V tile 32 KiB
      const int o = p * 8192 + tid * 16;
      const int row = o >> 7;
      const int c8 = ((o >> 4) & 7) ^ (row & 7);
      gload_lds16(vt + (size_t)(bh * 256 + row) * 1024 + kt * 64 + c8 * 8,
                  (char*)&Vs[buf][0] + o);
    }
  };

  stage(0, 0);

  // Q B-frags + q2, direct from global (once per block)
  short8 qfrag[4];
  const unsigned short* qbase = qk + (size_t)(b * 1024 + qr0 + l31) * 1024 + h * 64;
  #pragma unroll
  for (int ks = 0; ks < 4; ks++)
    qfrag[ks] = *(const short8*)(qbase + ks * 16 + lh * 8);
  const float q2v = q2g[(size_t)bh * 1024 + qr0 + l31];

  f32x16 acc[8] = {};
  __syncthreads();   // prologue stage visible

  for (int kt = 0; kt < 16; kt++) {
    const int cur = kt & 1;
    if (kt < 15) stage(kt + 1, cur ^ 1);   // in flight until the barrier

    uint4 pa[4];   // P A-frags, [k-16-slice] x 4 words
    #pragma unroll
    for (int mi = 0; mi < 2; mi++) {
      // S^T = mfma(K, Q): D[k_local][q], k rows mi*32..+31 of this tile
      f32x16 sacc = {};
      #pragma unroll
      for (int ks = 0; ks < 4; ks++) {
        const int row = mi * 32 + l31;
        const int sl = (ks * 2 + lh) ^ (row & 7);
        short8 kf = *(const short8*)((const char*)&Ks[cur][0] + row * 128 + sl * 16);
        sacc = __builtin_amdgcn_mfma_f32_32x32x16_bf16(kf, qfrag[ks], sacc, 0, 0, 0);
      }
      // d2 -> exp, all registers; k2 via broadcast global float4
      const float* k2p = k2g + (size_t)bh * 1024 + kt * 64 + mi * 32 + lh * 4;
      float pr[16];
      #pragma unroll
      for (int g = 0; g < 4; g++) {
        const float4 k2v = *(const float4*)(k2p + g * 8);
        #pragma unroll
        for (int j = 0; j < 4; j++) {
          float d2 = q2v + ((const float*)&k2v)[j] - 2.f * sacc[g * 4 + j];
          pr[g * 4 + j] = __expf(-fmaxf(d2, 0.f) * inv_s2);
        }
      }
      // pack to bf16 A-frags: 8 cvt_pk + 4 permlane32_swap per mi.
      // permlane32_swap(w0,w2): w0'={w0.lo,w2.lo}=word0, w2'={w0.hi,w2.hi}=word2.
      #pragma unroll
      for (int ksh = 0; ksh < 2; ksh++) {
        unsigned w0, w1, w2, w3;
        const int o = ksh * 8;
        asm("v_cvt_pk_bf16_f32 %0, %1, %2" : "=v"(w0) : "v"(pr[o + 0]), "v"(pr[o + 1]));
        asm("v_cvt_pk_bf16_f32 %0, %1, %2" : "=v"(w1) : "v"(pr[o + 2]), "v"(pr[o + 3]));
        asm("v_cvt_pk_bf16_f32 %0, %1, %2" : "=v"(w2) : "v"(pr[o + 4]), "v"(pr[o + 5]));
        asm("v_cvt_pk_bf16_f32 %0, %1, %2" : "=v"(w3) : "v"(pr[o + 6]), "v"(pr[o + 7]));
        asm("v_permlane32_swap_b32 %0, %1" : "+v"(w0), "+v"(w2));
        asm("v_permlane32_swap_b32 %0, %1" : "+v"(w1), "+v"(w3));
        pa[mi * 2 + ksh] = make_uint4(w0, w1, w2, w3);
      }
    }
    // PV: acc[ci] += P(32q x 64k) @ V(64k x 256c), V from swizzled LDS
    #pragma unroll
    for (int ci = 0; ci < 8; ci++) {
      #pragma unroll
      for (int ks = 0; ks < 4; ks++) {
        const int row = ci * 32 + l31;
        const int sl = (ks * 2 + lh) ^ (row & 7);
        short8 vf = *(const short8*)((const char*)&Vs[cur][0] + row * 128 + sl * 16);
        short8 paf = *(const short8*)&pa[ks];
        acc[ci] = __builtin_amdgcn_mfma_f32_32x32x16_bf16(paf, vf, acc[ci], 0, 0, 0);
      }
    }
    __syncthreads();   // cur reads done; stage(kt+1) drained (vmcnt0 at barrier)
  }

  const size_t row0 = (size_t)(b * 1024 + qr0);
  #pragma unroll
  for (int ci = 0; ci < 8; ci++) {
    #pragma unroll
    for (int r = 0; r < 16; r++) {
      const int q = (r & 3) + 8 * (r >> 2) + 4 * lh;
      aout[(row0 + q) * 2048 + h * 256 + ci * 32 + l31] = f2bf(acc[ci][r]);
    }
  }
}

extern "C" void kernel_launch(void* const* d_in, const int* in_sizes, int n_in,
                              void* d_out, int out_size, void* d_ws, size_t ws_size,
                              hipStream_t stream) {
  (void)in_sizes; (void)n_in; (void)out_size; (void)ws_size;
  const float* x      = (const float*)d_in[0];
  const float* t      = (const float*)d_in[1];
  const float* gamma  = (const float*)d_in[2];
  const float* beta   = (const float*)d_in[3];
  const float* pos    = (const float*)d_in[4];
  const float* Wqkv   = (const float*)d_in[5];
  const float* bqkv   = (const float*)d_in[6];
  const float* Wm     = (const float*)d_in[7];
  const float* bm     = (const float*)d_in[8];
  const float* Wt     = (const float*)d_in[9];
  const float* bt     = (const float*)d_in[10];
  const float* gamma1 = (const float*)d_in[11];
  const float* beta1  = (const float*)d_in[12];
  const float* Wf1    = (const float*)d_in[13];
  const float* bf1    = (const float*)d_in[14];
  const float* Wf2    = (const float*)d_in[15];
  const float* bf2    = (const float*)d_in[16];
  const float* scale  = (const float*)d_in[17];
  float* out = (float*)d_out;

  char* ws = (char*)d_ws;
  size_t off = 0;
  auto alloc = [&](size_t bytes) -> void* {
    void* p = ws + off;
    off += (bytes + 255) & ~(size_t)255;
    return p;
  };
  unsigned short* qkb   = (unsigned short*)alloc((size_t)8192 * 1024 * 2);
  unsigned short* vtb   = (unsigned short*)alloc((size_t)64 * 256 * 1024 * 2);
  unsigned short* aoutb = (unsigned short*)alloc((size_t)8192 * 2048 * 2);
  unsigned short* hbuf  = (unsigned short*)alloc((size_t)8192 * 256 * 2);
  unsigned short* ffbuf = (unsigned short*)alloc((size_t)8192 * 1024 * 2);
  float* x1             = (float*)alloc((size_t)8192 * 256 * 4);
  unsigned short* WqkvT = (unsigned short*)alloc((size_t)3072 * 256 * 2);
  unsigned short* WmT   = (unsigned short*)alloc((size_t)256 * 2048 * 2);
  unsigned short* Wf1T  = (unsigned short*)alloc((size_t)1024 * 256 * 2);
  unsigned short* Wf2T  = (unsigned short*)alloc((size_t)256 * 1024 * 2);
  float* partial = (float*)alloc((size_t)8 * 32 * 2 * 256 * 4);
  float* mean1   = (float*)alloc(8 * 256 * 4);
  float* rstd1   = (float*)alloc(8 * 256 * 4);
  float* mean2   = (float*)alloc(8 * 256 * 4);
  float* rstd2   = (float*)alloc(8 * 256 * 4);
  float* sig_ts  = (float*)alloc(8 * 1024 * 4);
  float* q2g     = (float*)alloc((size_t)64 * 1024 * 4);
  float* k2g     = (float*)alloc((size_t)64 * 1024 * 4);

  transpose_w<<<dim3(96, 8),  256, 0, stream>>>(Wqkv, WqkvT, 256, 3072);
  transpose_w<<<dim3(8, 64),  256, 0, stream>>>(Wm,   WmT,   2048, 256);
  transpose_w<<<dim3(32, 8),  256, 0, stream>>>(Wf1,  Wf1T,  256, 1024);
  transpose_w<<<dim3(8, 32),  256, 0, stream>>>(Wf2,  Wf2T,  1024, 256);

  stats_pass1<<<256, 256, 0, stream>>>(x, partial);
  stats_pass2<<<8, 256, 0, stream>>>(partial, mean1, rstd1);
  time_proj<<<dim3(4, 8), 256, 0, stream>>>(t, Wt, bt, sig_ts);
  norm_swish<true><<<2048, 256, 0, stream>>>(x, mean1, rstd1, gamma, beta, pos, hbuf);

  gemm2<0, 128><<<dim3(24, 64), 256, 0, stream>>>(hbuf, WqkvT, bqkv, nullptr, nullptr,
                                                  qkb, nullptr, vtb, 256, 3072);
  q2k2_kernel<<<2048, 256, 0, stream>>>(qkb, q2g, k2g);
  attn3<<<256, 512, 0, stream>>>(qkb, vtb, q2g, k2g, aoutb, scale);
  gemm2<1, 64><<<dim3(4, 64), 256, 0, stream>>>(aoutb, WmT, bm, x, nullptr,
                                                nullptr, x1, nullptr, 2048, 256);

  stats_pass1<<<256, 256, 0, stream>>>(x1, partial);
  stats_pass2<<<8, 256, 0, stream>>>(partial, mean2, rstd2);
  norm_swish<false><<<2048, 256, 0, stream>>>(x1, mean2, rstd2, gamma1, beta1, nullptr, hbuf);

  gemm2<2, 128><<<dim3(8, 64), 256, 0, stream>>>(hbuf, Wf1T, bf1, nullptr, sig_ts,
                                                 ffbuf, nullptr, nullptr, 256, 1024);
  gemm2<1, 64><<<dim3(4, 64), 256, 0, stream>>>(ffbuf, Wf2T, bf2, x1, nullptr,
                                                nullptr, out, nullptr, 1024, 256);
}

// Round 16
// 190.588 us; speedup vs baseline: 1.1020x; 1.0661x over previous
//
#include <hip/hip_runtime.h>
#include <math.h>

typedef __attribute__((ext_vector_type(4))) float f32x4;
typedef __attribute__((ext_vector_type(16))) float f32x16;
typedef __attribute__((ext_vector_type(8))) short short8;

#define DI __device__ __forceinline__

static constexpr int Bb = 8;
static constexpr int Nn = 1024;
static constexpr int Dd = 256;

DI unsigned short f2bf(float f) {
  union { float f; unsigned u; } v; v.f = f;
  unsigned r = v.u + 0x7fffu + ((v.u >> 16) & 1u);
  return (unsigned short)(r >> 16);
}
DI float bf2f(unsigned short h) {
  union { unsigned u; float f; } v; v.u = ((unsigned)h) << 16; return v.f;
}

DI void gload_lds16(const void* g, void* l) {
  __builtin_amdgcn_global_load_lds((const __attribute__((address_space(1))) unsigned int*)g,
                                   (__attribute__((address_space(3))) unsigned int*)l, 16, 0, 0);
}

// ---------------- stats over sequence dim (axis=1) ----------------
__global__ void stats_pass1(const float* __restrict__ x, float* __restrict__ partial) {
  int d = threadIdx.x;
  int b = blockIdx.x >> 5;
  int c = blockIdx.x & 31;
  const float* p = x + ((size_t)b * Nn + c * 32) * Dd + d;
  float s = 0.f, ss = 0.f;
  for (int i = 0; i < 32; i++) { float v = p[(size_t)i * Dd]; s += v; ss += v * v; }
  float* o = partial + ((size_t)(b * 32 + c) * 2) * Dd + d;
  o[0] = s; o[Dd] = ss;
}

__global__ void stats_pass2(const float* __restrict__ partial, float* __restrict__ mean,
                            float* __restrict__ rstd) {
  int d = threadIdx.x; int b = blockIdx.x;
  float s = 0.f, ss = 0.f;
  for (int c = 0; c < 32; c++) {
    s  += partial[((size_t)(b * 32 + c) * 2) * Dd + d];
    ss += partial[((size_t)(b * 32 + c) * 2) * Dd + Dd + d];
  }
  float m = s * (1.f / Nn);
  float var = ss * (1.f / Nn) - m * m;
  mean[b * Dd + d] = m;
  rstd[b * Dd + d] = rsqrtf(var + 1e-5f);
}

// ---------------- norm (+pos) + swish -> bf16 ----------------
template<bool POS>
__global__ void norm_swish(const float* __restrict__ x, const float* __restrict__ mean,
                           const float* __restrict__ rstd, const float* __restrict__ gamma,
                           const float* __restrict__ beta, const float* __restrict__ pos,
                           unsigned short* __restrict__ out) {
  size_t idx = ((size_t)blockIdx.x * 256 + threadIdx.x) * 4;
  int d = (int)(idx & (Dd - 1));
  size_t row = idx >> 8;
  int b = (int)(row >> 10);
  int n = (int)(row & (Nn - 1));
  const float4 xv = *(const float4*)(x + idx);
  const float4 gv = *(const float4*)(gamma + d);
  const float4 bv = *(const float4*)(beta + d);
  const float4 mv = *(const float4*)(mean + b * Dd + d);
  const float4 rv = *(const float4*)(rstd + b * Dd + d);
  float v[4]  = {xv.x, xv.y, xv.z, xv.w};
  float g[4]  = {gv.x, gv.y, gv.z, gv.w};
  float be[4] = {bv.x, bv.y, bv.z, bv.w};
  float mm[4] = {mv.x, mv.y, mv.z, mv.w};
  float rr[4] = {rv.x, rv.y, rv.z, rv.w};
  float pp[4] = {0.f, 0.f, 0.f, 0.f};
  if (POS) {
    const float4 pv = *(const float4*)(pos + (size_t)n * Dd + d);
    pp[0] = pv.x; pp[1] = pv.y; pp[2] = pv.z; pp[3] = pv.w;
  }
  ushort4 o;
  unsigned short* op = (unsigned short*)&o;
  #pragma unroll
  for (int j = 0; j < 4; j++) {
    float val = (v[j] - mm[j]) * rr[j] * g[j] + be[j];
    if (POS) val += pp[j];
    float sw = val / (1.f + __expf(-val));
    op[j] = f2bf(sw);
  }
  *(ushort4*)(out + idx) = o;
}

// ---------------- time projection ----------------
__global__ void time_proj(const float* __restrict__ t, const float* __restrict__ Wt,
                          const float* __restrict__ bt, float* __restrict__ sig_ts) {
  int j = blockIdx.x * 256 + threadIdx.x;
  int b = blockIdx.y;
  const float* tb = t + b * 256;
  float acc = bt[256 + j];
  for (int k = 0; k < 256; k++) acc += tb[k] * Wt[k * 1280 + 256 + j];
  sig_ts[b * 1024 + j] = 1.f / (1.f + __expf(-acc));
}

// ---------------- fused weight transposes f32 [R][C] -> bf16 [C][R] ----------------
// EXONERATED by R8/R14 identical-absmax evidence (outputs bit-identical to transpose_w).
DI void transpose_tile(const float* in, unsigned short* out, int R, int C,
                       int bx, int by) {
  __shared__ float tile[32][33];
  int c0 = bx * 32, r0 = by * 32;
  int tx = threadIdx.x & 31, ty = threadIdx.x >> 5;
  for (int i = ty; i < 32; i += 8)
    tile[i][tx] = in[(size_t)(r0 + i) * C + c0 + tx];
  __syncthreads();
  for (int i = ty; i < 32; i += 8)
    out[(size_t)(c0 + i) * R + r0 + tx] = f2bf(tile[tx][i]);
}

// grid: [0,768) Wqkv 256x3072 (96x8); [768,1280) Wm 2048x256 (8x64);
//       [1280,1536) Wf1 256x1024 (32x8); [1536,1792) Wf2 1024x256 (8x32)
__global__ void transpose4(const float* __restrict__ w0, unsigned short* __restrict__ o0,
                           const float* __restrict__ w1, unsigned short* __restrict__ o1,
                           const float* __restrict__ w2, unsigned short* __restrict__ o2,
                           const float* __restrict__ w3, unsigned short* __restrict__ o3) {
  int g = blockIdx.x;
  if (g < 768)        transpose_tile(w0, o0, 256, 3072, g % 96, g / 96);
  else if (g < 1280)  { g -= 768;  transpose_tile(w1, o1, 2048, 256, g % 8, g / 8); }
  else if (g < 1536)  { g -= 1280; transpose_tile(w2, o2, 256, 1024, g % 32, g / 32); }
  else                { g -= 1536; transpose_tile(w3, o3, 1024, 256, g % 8, g / 8); }
}

// ---------------- q2/k2 precompute from qk buffer ----------------
// qk: bf16 [8192][1024]; q2,k2: f32 [64][1024] (bh-major)
__global__ void q2k2_kernel(const unsigned short* __restrict__ qk,
                            float* __restrict__ q2, float* __restrict__ k2) {
  const int wave = threadIdx.x >> 6, lane = threadIdx.x & 63;
  const int r = blockIdx.x * 4 + wave;   // row 0..8191
  const int b = r >> 10, n = r & 1023;
  short8 v = *(const short8*)(qk + (size_t)r * 1024 + lane * 16);
  float s = 0.f;
  #pragma unroll
  for (int j = 0; j < 8; j++) { float f = bf2f(((unsigned short*)&v)[j]); s += f * f; }
  short8 v2 = *(const short8*)(qk + (size_t)r * 1024 + lane * 16 + 8);
  #pragma unroll
  for (int j = 0; j < 8; j++) { float f = bf2f(((unsigned short*)&v2)[j]); s += f * f; }
  s += __shfl_xor(s, 1);
  s += __shfl_xor(s, 2);
  if ((lane & 3) == 0) {
    const int seg = lane >> 2;                 // 0..15
    float* dst = (seg < 8) ? q2 : k2;
    dst[(size_t)(b * 8 + (seg & 7)) * 1024 + n] = s;
  }
}

// ---------------- GEMM (m97-style: linear LDS + global_load_lds) ----------------
// T1 XCD swizzle (validated R12). BN now parametric over {128,64,32}:
// BN=32 doubles grid for the N=256 deep-K GEMMs -> 2 blocks/CU latency hiding.
// EPI 0: qkv split epilogue; EPI 1: f32 out = acc+bias+res; EPI 2: gated swish -> bf16
template<int EPI, int BN>
__global__ __launch_bounds__(256, 3) void gemm2(
    const unsigned short* __restrict__ A, const unsigned short* __restrict__ BT,
    const float* __restrict__ bias, const float* __restrict__ res,
    const float* __restrict__ aux, unsigned short* __restrict__ obf,
    float* __restrict__ of, unsigned short* __restrict__ vtb, int K, int Ndim) {
  __shared__ __align__(16) unsigned short As[128 * 64];
  __shared__ __align__(16) unsigned short Bs[BN * 64];
  const int tid = threadIdx.x, lane = tid & 63, wave = tid >> 6;
  const int wr = wave >> 1, wc = wave & 1;
  constexpr int NI  = (BN == 128) ? 4 : (BN == 64 ? 2 : 1);
  constexpr int WCW = (BN == 128) ? 64 : (BN == 64 ? 32 : 16);
  const int nwg = gridDim.x * gridDim.y;
  const int orig = blockIdx.y * gridDim.x + blockIdx.x;
  const int swz = (orig & 7) * (nwg >> 3) + (orig >> 3);
  const int m0 = (swz / gridDim.x) * 128, n0 = (swz % gridDim.x) * BN;
  f32x4 acc[4][NI] = {};
  for (int k0 = 0; k0 < K; k0 += 64) {
    __syncthreads();
    #pragma unroll
    for (int p = 0; p < 4; p++) {
      const int o = p * 4096 + tid * 16;
      const int row = o >> 7, c8 = (o >> 4) & 7;
      gload_lds16(A + (size_t)(m0 + row) * K + k0 + c8 * 8, (char*)As + o);
    }
    #pragma unroll
    for (int p = 0; p < BN / 32; p++) {
      const int o = p * 4096 + tid * 16;
      const int row = o >> 7, c8 = (o >> 4) & 7;
      gload_lds16(BT + (size_t)(n0 + row) * K + k0 + c8 * 8, (char*)Bs + o);
    }
    __syncthreads();
    #pragma unroll
    for (int ks = 0; ks < 2; ks++) {
      short8 af[4], bfr[NI];
      #pragma unroll
      for (int i = 0; i < 4; i++)
        af[i] = *(const short8*)&As[(wr * 64 + i * 16 + (lane & 15)) * 64 + ks * 32 + (lane >> 4) * 8];
      #pragma unroll
      for (int i = 0; i < NI; i++)
        bfr[i] = *(const short8*)&Bs[(wc * WCW + i * 16 + (lane & 15)) * 64 + ks * 32 + (lane >> 4) * 8];
      #pragma unroll
      for (int mi = 0; mi < 4; mi++)
        #pragma unroll
        for (int ni = 0; ni < NI; ni++)
          acc[mi][ni] = __builtin_amdgcn_mfma_f32_16x16x32_bf16(af[mi], bfr[ni], acc[mi][ni], 0, 0, 0);
    }
  }
  const int rbase = m0 + wr * 64 + ((lane >> 4) << 2);
  const int cb = n0 + wc * WCW + (lane & 15);
  #pragma unroll
  for (int mi = 0; mi < 4; mi++) {
    #pragma unroll
    for (int ni = 0; ni < NI; ni++) {
      const int col = cb + ni * 16;
      const float bv = bias[col];
      const int r0_ = rbase + mi * 16;
      if (EPI == 0) {
        if (col < 1024) {
          #pragma unroll
          for (int j = 0; j < 4; j++)
            obf[(size_t)(r0_ + j) * 1024 + col] = f2bf(acc[mi][ni][j] + bv);
        } else {
          const int hh = (col - 1024) >> 8, cc = (col - 1024) & 255;
          const int b_ = r0_ >> 10, nb = r0_ & (Nn - 1);
          ushort4 pk;
          unsigned short* pp = (unsigned short*)&pk;
          #pragma unroll
          for (int j = 0; j < 4; j++) pp[j] = f2bf(acc[mi][ni][j] + bv);
          *(ushort4*)&vtb[((size_t)((b_ * 8 + hh) * 256 + cc)) * 1024 + nb] = pk;
        }
      } else if (EPI == 1) {
        #pragma unroll
        for (int j = 0; j < 4; j++) {
          size_t o = (size_t)(r0_ + j) * Ndim + col;
          of[o] = acc[mi][ni][j] + bv + res[o];
        }
      } else {
        const int b_ = r0_ >> 10;
        const float sg = aux[b_ * 1024 + col];
        #pragma unroll
        for (int j = 0; j < 4; j++) {
          float g = (acc[mi][ni][j] + bv) * sg;
          obf[(size_t)(r0_ + j) * Ndim + col] = f2bf(g / (1.f + __expf(-g)));
        }
      }
    }
  }
}

// ---------------- Gaussian-kernel attention v3 (round-6/12 PROVEN source, FROZEN) ----------------
// 8 waves x 32 q-rows each; P stays in registers (cvt_pk + permlane32_swap);
// q2/k2 precomputed; 1 barrier/iter; K/V double-buffered via global_load_lds.
__global__ __launch_bounds__(512, 2) void attn3(
    const unsigned short* __restrict__ qk, const unsigned short* __restrict__ vt,
    const float* __restrict__ q2g, const float* __restrict__ k2g,
    unsigned short* __restrict__ aout, const float* __restrict__ scale_p) {
  const int dd = blockIdx.x;
  const int bh = (dd & 7) + ((dd >> 5) << 3);   // 4 q-tiles of one bh -> same XCD
  const int qt = (dd >> 3) & 3;
  const int b = bh >> 3, h = bh & 7;
  const float sc = scale_p[0];
  const float inv_s2 = 1.f / (sc * sc);

  __shared__ __align__(16) unsigned short Ks[2][64 * 64];
  __shared__ __align__(16) unsigned short Vs[2][256 * 64];

  const int tid = threadIdx.x, lane = tid & 63, wave = tid >> 6;
  const int l31 = lane & 31, lh = lane >> 5;
  const int qr0 = qt * 256 + wave * 32;

  auto stage = [&](int kt, int buf) {
    { // K tile 8 KiB (inverse-swizzled global source, linear LDS dest)
      const int row = tid >> 3;
      const int c8 = (tid & 7) ^ (row & 7);
      gload_lds16(qk + (size_t)(b * 1024 + kt * 64 + row) * 1024 + 512 + h * 64 + c8 * 8,
                  (char*)&Ks[buf][0] + tid * 16);
    }
    #pragma unroll
    for (int p = 0; p < 4; p++) { // V tile 32 KiB
      const int o = p * 8192 + tid * 16;
      const int row = o >> 7;
      const int c8 = ((o >> 4) & 7) ^ (row & 7);
      gload_lds16(vt + (size_t)(bh * 256 + row) * 1024 + kt * 64 + c8 * 8,
                  (char*)&Vs[buf][0] + o);
    }
  };

  stage(0, 0);

  // Q B-frags + q2, direct from global (once per block)
  short8 qfrag[4];
  const unsigned short* qbase = qk + (size_t)(b * 1024 + qr0 + l31) * 1024 + h * 64;
  #pragma unroll
  for (int ks = 0; ks < 4; ks++)
    qfrag[ks] = *(const short8*)(qbase + ks * 16 + lh * 8);
  const float q2v = q2g[(size_t)bh * 1024 + qr0 + l31];

  f32x16 acc[8] = {};
  __syncthreads();   // prologue stage visible

  for (int kt = 0; kt < 16; kt++) {
    const int cur = kt & 1;
    if (kt < 15) stage(kt + 1, cur ^ 1);   // in flight until the barrier

    uint4 pa[4];   // P A-frags, [k-16-slice] x 4 words
    #pragma unroll
    for (int mi = 0; mi < 2; mi++) {
      // S^T = mfma(K, Q): D[k_local][q], k rows mi*32..+31 of this tile
      f32x16 sacc = {};
      #pragma unroll
      for (int ks = 0; ks < 4; ks++) {
        const int row = mi * 32 + l31;
        const int sl = (ks * 2 + lh) ^ (row & 7);
        short8 kf = *(const short8*)((const char*)&Ks[cur][0] + row * 128 + sl * 16);
        sacc = __builtin_amdgcn_mfma_f32_32x32x16_bf16(kf, qfrag[ks], sacc, 0, 0, 0);
      }
      // d2 -> exp, all registers; k2 via broadcast global float4
      const float* k2p = k2g + (size_t)bh * 1024 + kt * 64 + mi * 32 + lh * 4;
      float pr[16];
      #pragma unroll
      for (int g = 0; g < 4; g++) {
        const float4 k2v = *(const float4*)(k2p + g * 8);
        #pragma unroll
        for (int j = 0; j < 4; j++) {
          float d2 = q2v + ((const float*)&k2v)[j] - 2.f * sacc[g * 4 + j];
          pr[g * 4 + j] = __expf(-fmaxf(d2, 0.f) * inv_s2);
        }
      }
      // pack to bf16 A-frags: 8 cvt_pk + 4 permlane32_swap per mi.
      // permlane32_swap(w0,w2): w0'={w0.lo,w2.lo}=word0, w2'={w0.hi,w2.hi}=word2.
      #pragma unroll
      for (int ksh = 0; ksh < 2; ksh++) {
        unsigned w0, w1, w2, w3;
        const int o = ksh * 8;
        asm("v_cvt_pk_bf16_f32 %0, %1, %2" : "=v"(w0) : "v"(pr[o + 0]), "v"(pr[o + 1]));
        asm("v_cvt_pk_bf16_f32 %0, %1, %2" : "=v"(w1) : "v"(pr[o + 2]), "v"(pr[o + 3]));
        asm("v_cvt_pk_bf16_f32 %0, %1, %2" : "=v"(w2) : "v"(pr[o + 4]), "v"(pr[o + 5]));
        asm("v_cvt_pk_bf16_f32 %0, %1, %2" : "=v"(w3) : "v"(pr[o + 6]), "v"(pr[o + 7]));
        asm("v_permlane32_swap_b32 %0, %1" : "+v"(w0), "+v"(w2));
        asm("v_permlane32_swap_b32 %0, %1" : "+v"(w1), "+v"(w3));
        pa[mi * 2 + ksh] = make_uint4(w0, w1, w2, w3);
      }
    }
    // PV: acc[ci] += P(32q x 64k) @ V(64k x 256c), V from swizzled LDS
    #pragma unroll
    for (int ci = 0; ci < 8; ci++) {
      #pragma unroll
      for (int ks = 0; ks < 4; ks++) {
        const int row = ci * 32 + l31;
        const int sl = (ks * 2 + lh) ^ (row & 7);
        short8 vf = *(const short8*)((const char*)&Vs[cur][0] + row * 128 + sl * 16);
        short8 paf = *(const short8*)&pa[ks];
        acc[ci] = __builtin_amdgcn_mfma_f32_32x32x16_bf16(paf, vf, acc[ci], 0, 0, 0);
      }
    }
    __syncthreads();   // cur reads done; stage(kt+1) drained (vmcnt0 at barrier)
  }

  const size_t row0 = (size_t)(b * 1024 + qr0);
  #pragma unroll
  for (int ci = 0; ci < 8; ci++) {
    #pragma unroll
    for (int r = 0; r < 16; r++) {
      const int q = (r & 3) + 8 * (r >> 2) + 4 * lh;
      aout[(row0 + q) * 2048 + h * 256 + ci * 32 + l31] = f2bf(acc[ci][r]);
    }
  }
}

extern "C" void kernel_launch(void* const* d_in, const int* in_sizes, int n_in,
                              void* d_out, int out_size, void* d_ws, size_t ws_size,
                              hipStream_t stream) {
  (void)in_sizes; (void)n_in; (void)out_size; (void)ws_size;
  const float* x      = (const float*)d_in[0];
  const float* t      = (const float*)d_in[1];
  const float* gamma  = (const float*)d_in[2];
  const float* beta   = (const float*)d_in[3];
  const float* pos    = (const float*)d_in[4];
  const float* Wqkv   = (const float*)d_in[5];
  const float* bqkv   = (const float*)d_in[6];
  const float* Wm     = (const float*)d_in[7];
  const float* bm     = (const float*)d_in[8];
  const float* Wt     = (const float*)d_in[9];
  const float* bt     = (const float*)d_in[10];
  const float* gamma1 = (const float*)d_in[11];
  const float* beta1  = (const float*)d_in[12];
  const float* Wf1    = (const float*)d_in[13];
  const float* bf1    = (const float*)d_in[14];
  const float* Wf2    = (const float*)d_in[15];
  const float* bf2    = (const float*)d_in[16];
  const float* scale  = (const float*)d_in[17];
  float* out = (float*)d_out;

  char* ws = (char*)d_ws;
  size_t off = 0;
  auto alloc = [&](size_t bytes) -> void* {
    void* p = ws + off;
    off += (bytes + 255) & ~(size_t)255;
    return p;
  };
  unsigned short* qkb   = (unsigned short*)alloc((size_t)8192 * 1024 * 2);
  unsigned short* vtb   = (unsigned short*)alloc((size_t)64 * 256 * 1024 * 2);
  unsigned short* aoutb = (unsigned short*)alloc((size_t)8192 * 2048 * 2);
  unsigned short* hbuf  = (unsigned short*)alloc((size_t)8192 * 256 * 2);
  unsigned short* ffbuf = (unsigned short*)alloc((size_t)8192 * 1024 * 2);
  float* x1             = (float*)alloc((size_t)8192 * 256 * 4);
  unsigned short* WqkvT = (unsigned short*)alloc((size_t)3072 * 256 * 2);
  unsigned short* WmT   = (unsigned short*)alloc((size_t)256 * 2048 * 2);
  unsigned short* Wf1T  = (unsigned short*)alloc((size_t)1024 * 256 * 2);
  unsigned short* Wf2T  = (unsigned short*)alloc((size_t)256 * 1024 * 2);
  float* partial = (float*)alloc((size_t)8 * 32 * 2 * 256 * 4);
  float* mean1   = (float*)alloc(8 * 256 * 4);
  float* rstd1   = (float*)alloc(8 * 256 * 4);
  float* mean2   = (float*)alloc(8 * 256 * 4);
  float* rstd2   = (float*)alloc(8 * 256 * 4);
  float* sig_ts  = (float*)alloc(8 * 1024 * 4);
  float* q2g     = (float*)alloc((size_t)64 * 1024 * 4);
  float* k2g     = (float*)alloc((size_t)64 * 1024 * 4);

  transpose4<<<1792, 256, 0, stream>>>(Wqkv, WqkvT, Wm, WmT, Wf1, Wf1T, Wf2, Wf2T);

  stats_pass1<<<256, 256, 0, stream>>>(x, partial);
  stats_pass2<<<8, 256, 0, stream>>>(partial, mean1, rstd1);
  time_proj<<<dim3(4, 8), 256, 0, stream>>>(t, Wt, bt, sig_ts);
  norm_swish<true><<<2048, 256, 0, stream>>>(x, mean1, rstd1, gamma, beta, pos, hbuf);

  gemm2<0, 128><<<dim3(24, 64), 256, 0, stream>>>(hbuf, WqkvT, bqkv, nullptr, nullptr,
                                                  qkb, nullptr, vtb, 256, 3072);
  q2k2_kernel<<<2048, 256, 0, stream>>>(qkb, q2g, k2g);
  attn3<<<256, 512, 0, stream>>>(qkb, vtb, q2g, k2g, aoutb, scale);
  gemm2<1, 32><<<dim3(8, 64), 256, 0, stream>>>(aoutb, WmT, bm, x, nullptr,
                                                nullptr, x1, nullptr, 2048, 256);

  stats_pass1<<<256, 256, 0, stream>>>(x1, partial);
  stats_pass2<<<8, 256, 0, stream>>>(partial, mean2, rstd2);
  norm_swish<false><<<2048, 256, 0, stream>>>(x1, mean2, rstd2, gamma1, beta1, nullptr, hbuf);

  gemm2<2, 128><<<dim3(8, 64), 256, 0, stream>>>(hbuf, Wf1T, bf1, nullptr, sig_ts,
                                                 ffbuf, nullptr, nullptr, 256, 1024);
  gemm2<1, 32><<<dim3(8, 64), 256, 0, stream>>>(ffbuf, Wf2T, bf2, x1, nullptr,
                                                nullptr, out, nullptr, 1024, 256);
}

// Round 19
// 184.835 us; speedup vs baseline: 1.1363x; 1.0311x over previous
//
#include <hip/hip_runtime.h>
#include <math.h>

typedef __attribute__((ext_vector_type(4))) float f32x4;
typedef __attribute__((ext_vector_type(16))) float f32x16;
typedef __attribute__((ext_vector_type(8))) short short8;

#define DI __device__ __forceinline__

static constexpr int Bb = 8;
static constexpr int Nn = 1024;
static constexpr int Dd = 256;

DI unsigned short f2bf(float f) {
  union { float f; unsigned u; } v; v.f = f;
  unsigned r = v.u + 0x7fffu + ((v.u >> 16) & 1u);
  return (unsigned short)(r >> 16);
}
DI float bf2f(unsigned short h) {
  union { unsigned u; float f; } v; v.u = ((unsigned)h) << 16; return v.f;
}

DI void gload_lds16(const void* g, void* l) {
  __builtin_amdgcn_global_load_lds((const __attribute__((address_space(1))) unsigned int*)g,
                                   (__attribute__((address_space(3))) unsigned int*)l, 16, 0, 0);
}

// ---------------- stats over sequence dim (axis=1) ----------------
__global__ void stats_pass1(const float* __restrict__ x, float* __restrict__ partial) {
  int d = threadIdx.x;
  int b = blockIdx.x >> 5;
  int c = blockIdx.x & 31;
  const float* p = x + ((size_t)b * Nn + c * 32) * Dd + d;
  float s = 0.f, ss = 0.f;
  for (int i = 0; i < 32; i++) { float v = p[(size_t)i * Dd]; s += v; ss += v * v; }
  float* o = partial + ((size_t)(b * 32 + c) * 2) * Dd + d;
  o[0] = s; o[Dd] = ss;
}

__global__ void stats_pass2(const float* __restrict__ partial, float* __restrict__ mean,
                            float* __restrict__ rstd) {
  int d = threadIdx.x; int b = blockIdx.x;
  float s = 0.f, ss = 0.f;
  for (int c = 0; c < 32; c++) {
    s  += partial[((size_t)(b * 32 + c) * 2) * Dd + d];
    ss += partial[((size_t)(b * 32 + c) * 2) * Dd + Dd + d];
  }
  float m = s * (1.f / Nn);
  float var = ss * (1.f / Nn) - m * m;
  mean[b * Dd + d] = m;
  rstd[b * Dd + d] = rsqrtf(var + 1e-5f);
}

// ---------------- norm (+pos) + swish -> bf16 ----------------
template<bool POS>
__global__ void norm_swish(const float* __restrict__ x, const float* __restrict__ mean,
                           const float* __restrict__ rstd, const float* __restrict__ gamma,
                           const float* __restrict__ beta, const float* __restrict__ pos,
                           unsigned short* __restrict__ out) {
  size_t idx = ((size_t)blockIdx.x * 256 + threadIdx.x) * 4;
  int d = (int)(idx & (Dd - 1));
  size_t row = idx >> 8;
  int b = (int)(row >> 10);
  int n = (int)(row & (Nn - 1));
  const float4 xv = *(const float4*)(x + idx);
  const float4 gv = *(const float4*)(gamma + d);
  const float4 bv = *(const float4*)(beta + d);
  const float4 mv = *(const float4*)(mean + b * Dd + d);
  const float4 rv = *(const float4*)(rstd + b * Dd + d);
  float v[4]  = {xv.x, xv.y, xv.z, xv.w};
  float g[4]  = {gv.x, gv.y, gv.z, gv.w};
  float be[4] = {bv.x, bv.y, bv.z, bv.w};
  float mm[4] = {mv.x, mv.y, mv.z, mv.w};
  float rr[4] = {rv.x, rv.y, rv.z, rv.w};
  float pp[4] = {0.f, 0.f, 0.f, 0.f};
  if (POS) {
    const float4 pv = *(const float4*)(pos + (size_t)n * Dd + d);
    pp[0] = pv.x; pp[1] = pv.y; pp[2] = pv.z; pp[3] = pv.w;
  }
  ushort4 o;
  unsigned short* op = (unsigned short*)&o;
  #pragma unroll
  for (int j = 0; j < 4; j++) {
    float val = (v[j] - mm[j]) * rr[j] * g[j] + be[j];
    if (POS) val += pp[j];
    float sw = val / (1.f + __expf(-val));
    op[j] = f2bf(sw);
  }
  *(ushort4*)(out + idx) = o;
}

// ---------------- fused weight transposes + time projection ----------------
// transpose_tile EXONERATED (R8/R14 bit-identical evidence).
DI void transpose_tile(const float* in, unsigned short* out, int R, int C,
                       int bx, int by) {
  __shared__ float tile[32][33];
  int c0 = bx * 32, r0 = by * 32;
  int tx = threadIdx.x & 31, ty = threadIdx.x >> 5;
  for (int i = ty; i < 32; i += 8)
    tile[i][tx] = in[(size_t)(r0 + i) * C + c0 + tx];
  __syncthreads();
  for (int i = ty; i < 32; i += 8)
    out[(size_t)(c0 + i) * R + r0 + tx] = f2bf(tile[tx][i]);
}

// grid: [0,768) Wqkv 256x3072 (96x8); [768,1280) Wm 2048x256 (8x64);
//       [1280,1536) Wf1 256x1024 (32x8); [1536,1792) Wf2 1024x256 (8x32);
//       [1792,1824) time_proj (32 blocks: gg&3 = j-chunk, gg>>2 = b)
__global__ void transpose4(const float* __restrict__ w0, unsigned short* __restrict__ o0,
                           const float* __restrict__ w1, unsigned short* __restrict__ o1,
                           const float* __restrict__ w2, unsigned short* __restrict__ o2,
                           const float* __restrict__ w3, unsigned short* __restrict__ o3,
                           const float* __restrict__ t, const float* __restrict__ Wt,
                           const float* __restrict__ bt, float* __restrict__ sig_ts) {
  int g = blockIdx.x;
  if (g < 768)        transpose_tile(w0, o0, 256, 3072, g % 96, g / 96);
  else if (g < 1280)  { g -= 768;  transpose_tile(w1, o1, 2048, 256, g % 8, g / 8); }
  else if (g < 1536)  { g -= 1280; transpose_tile(w2, o2, 256, 1024, g % 32, g / 32); }
  else if (g < 1792)  { g -= 1536; transpose_tile(w3, o3, 1024, 256, g % 8, g / 8); }
  else {
    g -= 1792;
    const int j = (g & 3) * 256 + threadIdx.x;   // 0..1023
    const int b = g >> 2;                        // 0..7
    const float* tb = t + b * 256;
    float acc = bt[256 + j];
    for (int k = 0; k < 256; k++) acc += tb[k] * Wt[k * 1280 + 256 + j];
    sig_ts[b * 1024 + j] = 1.f / (1.f + __expf(-acc));
  }
}

// ---------------- GEMM (m97-style: linear LDS + global_load_lds) ----------------
// T1 XCD swizzle (validated R12). BN parametric {128,64,32}.
// EPI 0: qkv split epilogue + FUSED q2/k2 row-sum reduction (uses the SAME
//        bf16-rounded values as the qkb store -> exact consistency with qfrag).
// EPI 1: f32 out = acc+bias+res; EPI 2: gated swish -> bf16
template<int EPI, int BN>
__global__ __launch_bounds__(256, 3) void gemm2(
    const unsigned short* __restrict__ A, const unsigned short* __restrict__ BT,
    const float* __restrict__ bias, const float* __restrict__ res,
    const float* __restrict__ aux, unsigned short* __restrict__ obf,
    float* __restrict__ of, unsigned short* __restrict__ vtb, int K, int Ndim,
    float* __restrict__ q2o, float* __restrict__ k2o) {
  __shared__ __align__(16) unsigned short As[128 * 64];
  __shared__ __align__(16) unsigned short Bs[BN * 64];
  const int tid = threadIdx.x, lane = tid & 63, wave = tid >> 6;
  const int wr = wave >> 1, wc = wave & 1;
  constexpr int NI  = (BN == 128) ? 4 : (BN == 64 ? 2 : 1);
  constexpr int WCW = (BN == 128) ? 64 : (BN == 64 ? 32 : 16);
  const int nwg = gridDim.x * gridDim.y;
  const int orig = blockIdx.y * gridDim.x + blockIdx.x;
  const int swz = (orig & 7) * (nwg >> 3) + (orig >> 3);
  const int m0 = (swz / gridDim.x) * 128, n0 = (swz % gridDim.x) * BN;
  f32x4 acc[4][NI] = {};
  for (int k0 = 0; k0 < K; k0 += 64) {
    __syncthreads();
    #pragma unroll
    for (int p = 0; p < 4; p++) {
      const int o = p * 4096 + tid * 16;
      const int row = o >> 7, c8 = (o >> 4) & 7;
      gload_lds16(A + (size_t)(m0 + row) * K + k0 + c8 * 8, (char*)As + o);
    }
    #pragma unroll
    for (int p = 0; p < BN / 32; p++) {
      const int o = p * 4096 + tid * 16;
      const int row = o >> 7, c8 = (o >> 4) & 7;
      gload_lds16(BT + (size_t)(n0 + row) * K + k0 + c8 * 8, (char*)Bs + o);
    }
    __syncthreads();
    #pragma unroll
    for (int ks = 0; ks < 2; ks++) {
      short8 af[4], bfr[NI];
      #pragma unroll
      for (int i = 0; i < 4; i++)
        af[i] = *(const short8*)&As[(wr * 64 + i * 16 + (lane & 15)) * 64 + ks * 32 + (lane >> 4) * 8];
      #pragma unroll
      for (int i = 0; i < NI; i++)
        bfr[i] = *(const short8*)&Bs[(wc * WCW + i * 16 + (lane & 15)) * 64 + ks * 32 + (lane >> 4) * 8];
      #pragma unroll
      for (int mi = 0; mi < 4; mi++)
        #pragma unroll
        for (int ni = 0; ni < NI; ni++)
          acc[mi][ni] = __builtin_amdgcn_mfma_f32_16x16x32_bf16(af[mi], bfr[ni], acc[mi][ni], 0, 0, 0);
    }
  }
  const int rbase = m0 + wr * 64 + ((lane >> 4) << 2);
  const int cb = n0 + wc * WCW + (lane & 15);
  float rowsum[4][4];   // [mi][j] — only used by EPI 0 q/k blocks
  if (EPI == 0) {
    #pragma unroll
    for (int mi = 0; mi < 4; mi++)
      #pragma unroll
      for (int j = 0; j < 4; j++) rowsum[mi][j] = 0.f;
  }
  #pragma unroll
  for (int mi = 0; mi < 4; mi++) {
    #pragma unroll
    for (int ni = 0; ni < NI; ni++) {
      const int col = cb + ni * 16;
      const float bv = bias[col];
      const int r0_ = rbase + mi * 16;
      if (EPI == 0) {
        if (col < 1024) {
          #pragma unroll
          for (int j = 0; j < 4; j++) {
            unsigned short u = f2bf(acc[mi][ni][j] + bv);
            obf[(size_t)(r0_ + j) * 1024 + col] = u;
            float vb = bf2f(u);
            rowsum[mi][j] += vb * vb;
          }
        } else {
          const int hh = (col - 1024) >> 8, cc = (col - 1024) & 255;
          const int b_ = r0_ >> 10, nb = r0_ & (Nn - 1);
          ushort4 pk;
          unsigned short* pp = (unsigned short*)&pk;
          #pragma unroll
          for (int j = 0; j < 4; j++) pp[j] = f2bf(acc[mi][ni][j] + bv);
          *(ushort4*)&vtb[((size_t)((b_ * 8 + hh) * 256 + cc)) * 1024 + nb] = pk;
        }
      } else if (EPI == 1) {
        #pragma unroll
        for (int j = 0; j < 4; j++) {
          size_t o = (size_t)(r0_ + j) * Ndim + col;
          of[o] = acc[mi][ni][j] + bv + res[o];
        }
      } else {
        const int b_ = r0_ >> 10;
        const float sg = aux[b_ * 1024 + col];
        #pragma unroll
        for (int j = 0; j < 4; j++) {
          float g = (acc[mi][ni][j] + bv) * sg;
          obf[(size_t)(r0_ + j) * Ndim + col] = f2bf(g / (1.f + __expf(-g)));
        }
      }
    }
  }
  // Fused q2/k2: this wave's 64-col chunk is one head's q or k slice.
  if (EPI == 0) {
    const int chunk64 = n0 + wc * 64;
    if (chunk64 < 1024) {
      const int chunk = chunk64 >> 6;               // 0..15
      float* dst = (chunk < 8) ? q2o : k2o;
      const int h = chunk & 7;
      #pragma unroll
      for (int mi = 0; mi < 4; mi++) {
        #pragma unroll
        for (int j = 0; j < 4; j++) {
          float s = rowsum[mi][j];
          s += __shfl_xor(s, 1);
          s += __shfl_xor(s, 2);
          s += __shfl_xor(s, 4);
          s += __shfl_xor(s, 8);
          if ((lane & 15) == 0) {
            const int row = rbase + mi * 16 + j;
            dst[(size_t)((row >> 10) * 8 + h) * 1024 + (row & 1023)] = s;
          }
        }
      }
    }
  }
}

// ---------------- Gaussian-kernel attention v3 (round-6/12 PROVEN source, FROZEN) ----------------
__global__ __launch_bounds__(512, 2) void attn3(
    const unsigned short* __restrict__ qk, const unsigned short* __restrict__ vt,
    const float* __restrict__ q2g, const float* __restrict__ k2g,
    unsigned short* __restrict__ aout, const float* __restrict__ scale_p) {
  const int dd = blockIdx.x;
  const int bh = (dd & 7) + ((dd >> 5) << 3);   // 4 q-tiles of one bh -> same XCD
  const int qt = (dd >> 3) & 3;
  const int b = bh >> 3, h = bh & 7;
  const float sc = scale_p[0];
  const float inv_s2 = 1.f / (sc * sc);

  __shared__ __align__(16) unsigned short Ks[2][64 * 64];
  __shared__ __align__(16) unsigned short Vs[2][256 * 64];

  const int tid = threadIdx.x, lane = tid & 63, wave = tid >> 6;
  const int l31 = lane & 31, lh = lane >> 5;
  const int qr0 = qt * 256 + wave * 32;

  auto stage = [&](int kt, int buf) {
    { // K tile 8 KiB (inverse-swizzled global source, linear LDS dest)
      const int row = tid >> 3;
      const int c8 = (tid & 7) ^ (row & 7);
      gload_lds16(qk + (size_t)(b * 1024 + kt * 64 + row) * 1024 + 512 + h * 64 + c8 * 8,
                  (char*)&Ks[buf][0] + tid * 16);
    }
    #pragma unroll
    for (int p = 0; p < 4; p++) { // V tile 32 KiB
      const int o = p * 8192 + tid * 16;
      const int row = o >> 7;
      const int c8 = ((o >> 4) & 7) ^ (row & 7);
      gload_lds16(vt + (size_t)(bh * 256 + row) * 1024 + kt * 64 + c8 * 8,
                  (char*)&Vs[buf][0] + o);
    }
  };

  stage(0, 0);

  // Q B-frags + q2, direct from global (once per block)
  short8 qfrag[4];
  const unsigned short* qbase = qk + (size_t)(b * 1024 + qr0 + l31) * 1024 + h * 64;
  #pragma unroll
  for (int ks = 0; ks < 4; ks++)
    qfrag[ks] = *(const short8*)(qbase + ks * 16 + lh * 8);
  const float q2v = q2g[(size_t)bh * 1024 + qr0 + l31];

  f32x16 acc[8] = {};
  __syncthreads();   // prologue stage visible

  for (int kt = 0; kt < 16; kt++) {
    const int cur = kt & 1;
    if (kt < 15) stage(kt + 1, cur ^ 1);   // in flight until the barrier

    uint4 pa[4];   // P A-frags, [k-16-slice] x 4 words
    #pragma unroll
    for (int mi = 0; mi < 2; mi++) {
      // S^T = mfma(K, Q): D[k_local][q], k rows mi*32..+31 of this tile
      f32x16 sacc = {};
      #pragma unroll
      for (int ks = 0; ks < 4; ks++) {
        const int row = mi * 32 + l31;
        const int sl = (ks * 2 + lh) ^ (row & 7);
        short8 kf = *(const short8*)((const char*)&Ks[cur][0] + row * 128 + sl * 16);
        sacc = __builtin_amdgcn_mfma_f32_32x32x16_bf16(kf, qfrag[ks], sacc, 0, 0, 0);
      }
      // d2 -> exp, all registers; k2 via broadcast global float4
      const float* k2p = k2g + (size_t)bh * 1024 + kt * 64 + mi * 32 + lh * 4;
      float pr[16];
      #pragma unroll
      for (int g = 0; g < 4; g++) {
        const float4 k2v = *(const float4*)(k2p + g * 8);
        #pragma unroll
        for (int j = 0; j < 4; j++) {
          float d2 = q2v + ((const float*)&k2v)[j] - 2.f * sacc[g * 4 + j];
          pr[g * 4 + j] = __expf(-fmaxf(d2, 0.f) * inv_s2);
        }
      }
      // pack to bf16 A-frags: 8 cvt_pk + 4 permlane32_swap per mi.
      // permlane32_swap(w0,w2): w0'={w0.lo,w2.lo}=word0, w2'={w0.hi,w2.hi}=word2.
      #pragma unroll
      for (int ksh = 0; ksh < 2; ksh++) {
        unsigned w0, w1, w2, w3;
        const int o = ksh * 8;
        asm("v_cvt_pk_bf16_f32 %0, %1, %2" : "=v"(w0) : "v"(pr[o + 0]), "v"(pr[o + 1]));
        asm("v_cvt_pk_bf16_f32 %0, %1, %2" : "=v"(w1) : "v"(pr[o + 2]), "v"(pr[o + 3]));
        asm("v_cvt_pk_bf16_f32 %0, %1, %2" : "=v"(w2) : "v"(pr[o + 4]), "v"(pr[o + 5]));
        asm("v_cvt_pk_bf16_f32 %0, %1, %2" : "=v"(w3) : "v"(pr[o + 6]), "v"(pr[o + 7]));
        asm("v_permlane32_swap_b32 %0, %1" : "+v"(w0), "+v"(w2));
        asm("v_permlane32_swap_b32 %0, %1" : "+v"(w1), "+v"(w3));
        pa[mi * 2 + ksh] = make_uint4(w0, w1, w2, w3);
      }
    }
    // PV: acc[ci] += P(32q x 64k) @ V(64k x 256c), V from swizzled LDS
    #pragma unroll
    for (int ci = 0; ci < 8; ci++) {
      #pragma unroll
      for (int ks = 0; ks < 4; ks++) {
        const int row = ci * 32 + l31;
        const int sl = (ks * 2 + lh) ^ (row & 7);
        short8 vf = *(const short8*)((const char*)&Vs[cur][0] + row * 128 + sl * 16);
        short8 paf = *(const short8*)&pa[ks];
        acc[ci] = __builtin_amdgcn_mfma_f32_32x32x16_bf16(paf, vf, acc[ci], 0, 0, 0);
      }
    }
    __syncthreads();   // cur reads done; stage(kt+1) drained (vmcnt0 at barrier)
  }

  const size_t row0 = (size_t)(b * 1024 + qr0);
  #pragma unroll
  for (int ci = 0; ci < 8; ci++) {
    #pragma unroll
    for (int r = 0; r < 16; r++) {
      const int q = (r & 3) + 8 * (r >> 2) + 4 * lh;
      aout[(row0 + q) * 2048 + h * 256 + ci * 32 + l31] = f2bf(acc[ci][r]);
    }
  }
}

extern "C" void kernel_launch(void* const* d_in, const int* in_sizes, int n_in,
                              void* d_out, int out_size, void* d_ws, size_t ws_size,
                              hipStream_t stream) {
  (void)in_sizes; (void)n_in; (void)out_size; (void)ws_size;
  const float* x      = (const float*)d_in[0];
  const float* t      = (const float*)d_in[1];
  const float* gamma  = (const float*)d_in[2];
  const float* beta   = (const float*)d_in[3];
  const float* pos    = (const float*)d_in[4];
  const float* Wqkv   = (const float*)d_in[5];
  const float* bqkv   = (const float*)d_in[6];
  const float* Wm     = (const float*)d_in[7];
  const float* bm     = (const float*)d_in[8];
  const float* Wt     = (const float*)d_in[9];
  const float* bt     = (const float*)d_in[10];
  const float* gamma1 = (const float*)d_in[11];
  const float* beta1  = (const float*)d_in[12];
  const float* Wf1    = (const float*)d_in[13];
  const float* bf1    = (const float*)d_in[14];
  const float* Wf2    = (const float*)d_in[15];
  const float* bf2    = (const float*)d_in[16];
  const float* scale  = (const float*)d_in[17];
  float* out = (float*)d_out;

  char* ws = (char*)d_ws;
  size_t off = 0;
  auto alloc = [&](size_t bytes) -> void* {
    void* p = ws + off;
    off += (bytes + 255) & ~(size_t)255;
    return p;
  };
  unsigned short* qkb   = (unsigned short*)alloc((size_t)8192 * 1024 * 2);
  unsigned short* vtb   = (unsigned short*)alloc((size_t)64 * 256 * 1024 * 2);
  unsigned short* aoutb = (unsigned short*)alloc((size_t)8192 * 2048 * 2);
  unsigned short* hbuf  = (unsigned short*)alloc((size_t)8192 * 256 * 2);
  unsigned short* ffbuf = (unsigned short*)alloc((size_t)8192 * 1024 * 2);
  float* x1             = (float*)alloc((size_t)8192 * 256 * 4);
  unsigned short* WqkvT = (unsigned short*)alloc((size_t)3072 * 256 * 2);
  unsigned short* WmT   = (unsigned short*)alloc((size_t)256 * 2048 * 2);
  unsigned short* Wf1T  = (unsigned short*)alloc((size_t)1024 * 256 * 2);
  unsigned short* Wf2T  = (unsigned short*)alloc((size_t)256 * 1024 * 2);
  float* partial = (float*)alloc((size_t)8 * 32 * 2 * 256 * 4);
  float* mean1   = (float*)alloc(8 * 256 * 4);
  float* rstd1   = (float*)alloc(8 * 256 * 4);
  float* mean2   = (float*)alloc(8 * 256 * 4);
  float* rstd2   = (float*)alloc(8 * 256 * 4);
  float* sig_ts  = (float*)alloc(8 * 1024 * 4);
  float* q2g     = (float*)alloc((size_t)64 * 1024 * 4);
  float* k2g     = (float*)alloc((size_t)64 * 1024 * 4);

  transpose4<<<1824, 256, 0, stream>>>(Wqkv, WqkvT, Wm, WmT, Wf1, Wf1T, Wf2, Wf2T,
                                       t, Wt, bt, sig_ts);

  stats_pass1<<<256, 256, 0, stream>>>(x, partial);
  stats_pass2<<<8, 256, 0, stream>>>(partial, mean1, rstd1);
  norm_swish<true><<<2048, 256, 0, stream>>>(x, mean1, rstd1, gamma, beta, pos, hbuf);

  gemm2<0, 128><<<dim3(24, 64), 256, 0, stream>>>(hbuf, WqkvT, bqkv, nullptr, nullptr,
                                                  qkb, nullptr, vtb, 256, 3072, q2g, k2g);
  attn3<<<256, 512, 0, stream>>>(qkb, vtb, q2g, k2g, aoutb, scale);
  gemm2<1, 32><<<dim3(8, 64), 256, 0, stream>>>(aoutb, WmT, bm, x, nullptr,
                                                nullptr, x1, nullptr, 2048, 256,
                                                nullptr, nullptr);

  stats_pass1<<<256, 256, 0, stream>>>(x1, partial);
  stats_pass2<<<8, 256, 0, stream>>>(partial, mean2, rstd2);
  norm_swish<false><<<2048, 256, 0, stream>>>(x1, mean2, rstd2, gamma1, beta1, nullptr, hbuf);

  gemm2<2, 128><<<dim3(8, 64), 256, 0, stream>>>(hbuf, Wf1T, bf1, nullptr, sig_ts,
                                                 ffbuf, nullptr, nullptr, 256, 1024,
                                                 nullptr, nullptr);
  gemm2<1, 32><<<dim3(8, 64), 256, 0, stream>>>(ffbuf, Wf2T, bf2, x1, nullptr,
                                                nullptr, out, nullptr, 1024, 256,
                                                nullptr, nullptr);
}

// Round 20
// 181.024 us; speedup vs baseline: 1.1602x; 1.0210x over previous
//
#include <hip/hip_runtime.h>
#include <math.h>

typedef __attribute__((ext_vector_type(4))) float f32x4;
typedef __attribute__((ext_vector_type(16))) float f32x16;
typedef __attribute__((ext_vector_type(8))) short short8;

#define DI __device__ __forceinline__

static constexpr int Bb = 8;
static constexpr int Nn = 1024;
static constexpr int Dd = 256;

DI unsigned short f2bf(float f) {
  union { float f; unsigned u; } v; v.f = f;
  unsigned r = v.u + 0x7fffu + ((v.u >> 16) & 1u);
  return (unsigned short)(r >> 16);
}
DI float bf2f(unsigned short h) {
  union { unsigned u; float f; } v; v.u = ((unsigned)h) << 16; return v.f;
}

DI void gload_lds16(const void* g, void* l) {
  __builtin_amdgcn_global_load_lds((const __attribute__((address_space(1))) unsigned int*)g,
                                   (__attribute__((address_space(3))) unsigned int*)l, 16, 0, 0);
}

// ---------------- stats over sequence dim (axis=1) ----------------
__global__ void stats_pass1(const float* __restrict__ x, float* __restrict__ partial) {
  int d = threadIdx.x;
  int b = blockIdx.x >> 5;
  int c = blockIdx.x & 31;
  const float* p = x + ((size_t)b * Nn + c * 32) * Dd + d;
  float s = 0.f, ss = 0.f;
  for (int i = 0; i < 32; i++) { float v = p[(size_t)i * Dd]; s += v; ss += v * v; }
  float* o = partial + ((size_t)(b * 32 + c) * 2) * Dd + d;
  o[0] = s; o[Dd] = ss;
}

__global__ void stats_pass2(const float* __restrict__ partial, float* __restrict__ mean,
                            float* __restrict__ rstd) {
  int d = threadIdx.x; int b = blockIdx.x;
  float s = 0.f, ss = 0.f;
  for (int c = 0; c < 32; c++) {
    s  += partial[((size_t)(b * 32 + c) * 2) * Dd + d];
    ss += partial[((size_t)(b * 32 + c) * 2) * Dd + Dd + d];
  }
  float m = s * (1.f / Nn);
  float var = ss * (1.f / Nn) - m * m;
  mean[b * Dd + d] = m;
  rstd[b * Dd + d] = rsqrtf(var + 1e-5f);
}

// ---------------- norm (+pos) + swish -> bf16 ----------------
template<bool POS>
__global__ void norm_swish(const float* __restrict__ x, const float* __restrict__ mean,
                           const float* __restrict__ rstd, const float* __restrict__ gamma,
                           const float* __restrict__ beta, const float* __restrict__ pos,
                           unsigned short* __restrict__ out) {
  size_t idx = ((size_t)blockIdx.x * 256 + threadIdx.x) * 4;
  int d = (int)(idx & (Dd - 1));
  size_t row = idx >> 8;
  int b = (int)(row >> 10);
  int n = (int)(row & (Nn - 1));
  const float4 xv = *(const float4*)(x + idx);
  const float4 gv = *(const float4*)(gamma + d);
  const float4 bv = *(const float4*)(beta + d);
  const float4 mv = *(const float4*)(mean + b * Dd + d);
  const float4 rv = *(const float4*)(rstd + b * Dd + d);
  float v[4]  = {xv.x, xv.y, xv.z, xv.w};
  float g[4]  = {gv.x, gv.y, gv.z, gv.w};
  float be[4] = {bv.x, bv.y, bv.z, bv.w};
  float mm[4] = {mv.x, mv.y, mv.z, mv.w};
  float rr[4] = {rv.x, rv.y, rv.z, rv.w};
  float pp[4] = {0.f, 0.f, 0.f, 0.f};
  if (POS) {
    const float4 pv = *(const float4*)(pos + (size_t)n * Dd + d);
    pp[0] = pv.x; pp[1] = pv.y; pp[2] = pv.z; pp[3] = pv.w;
  }
  ushort4 o;
  unsigned short* op = (unsigned short*)&o;
  #pragma unroll
  for (int j = 0; j < 4; j++) {
    float val = (v[j] - mm[j]) * rr[j] * g[j] + be[j];
    if (POS) val += pp[j];
    float sw = val / (1.f + __expf(-val));
    op[j] = f2bf(sw);
  }
  *(ushort4*)(out + idx) = o;
}

// ---------------- fused weight transposes + time projection ----------------
// transpose_tile EXONERATED (R8/R14 bit-identical evidence).
DI void transpose_tile(const float* in, unsigned short* out, int R, int C,
                       int bx, int by) {
  __shared__ float tile[32][33];
  int c0 = bx * 32, r0 = by * 32;
  int tx = threadIdx.x & 31, ty = threadIdx.x >> 5;
  for (int i = ty; i < 32; i += 8)
    tile[i][tx] = in[(size_t)(r0 + i) * C + c0 + tx];
  __syncthreads();
  for (int i = ty; i < 32; i += 8)
    out[(size_t)(c0 + i) * R + r0 + tx] = f2bf(tile[tx][i]);
}

// grid: [0,768) Wqkv 256x3072 (96x8); [768,1280) Wm 2048x256 (8x64);
//       [1280,1536) Wf1 256x1024 (32x8); [1536,1792) Wf2 1024x256 (8x32);
//       [1792,1824) time_proj (32 blocks: gg&3 = j-chunk, gg>>2 = b)
__global__ void transpose4(const float* __restrict__ w0, unsigned short* __restrict__ o0,
                           const float* __restrict__ w1, unsigned short* __restrict__ o1,
                           const float* __restrict__ w2, unsigned short* __restrict__ o2,
                           const float* __restrict__ w3, unsigned short* __restrict__ o3,
                           const float* __restrict__ t, const float* __restrict__ Wt,
                           const float* __restrict__ bt, float* __restrict__ sig_ts) {
  int g = blockIdx.x;
  if (g < 768)        transpose_tile(w0, o0, 256, 3072, g % 96, g / 96);
  else if (g < 1280)  { g -= 768;  transpose_tile(w1, o1, 2048, 256, g % 8, g / 8); }
  else if (g < 1536)  { g -= 1280; transpose_tile(w2, o2, 256, 1024, g % 32, g / 32); }
  else if (g < 1792)  { g -= 1536; transpose_tile(w3, o3, 1024, 256, g % 8, g / 8); }
  else {
    g -= 1792;
    const int j = (g & 3) * 256 + threadIdx.x;   // 0..1023
    const int b = g >> 2;                        // 0..7
    const float* tb = t + b * 256;
    float acc = bt[256 + j];
    for (int k = 0; k < 256; k++) acc += tb[k] * Wt[k * 1280 + 256 + j];
    sig_ts[b * 1024 + j] = 1.f / (1.f + __expf(-acc));
  }
}

// ---------------- GEMM (m97-style: linear LDS + global_load_lds) ----------------
// T1 XCD swizzle (validated R12). BN parametric {128,64,32}.
// EPI 0: qkv split epilogue + FUSED q2/k2 row-sum reduction.
// EPI 1: f32 out = acc+bias+res.
// EPI 2: gated swish -> bf16.
// EPI 3: EPI 1 + FUSED seq-stats partials (BN=32 only: each thread's outputs
//        live in ONE column; mi<2 -> chunk c, mi>=2 -> c+1; shfl_xor(16,32)
//        folds the 4 lanes sharing a column; q2o receives the partial buffer).
template<int EPI, int BN>
__global__ __launch_bounds__(256, 3) void gemm2(
    const unsigned short* __restrict__ A, const unsigned short* __restrict__ BT,
    const float* __restrict__ bias, const float* __restrict__ res,
    const float* __restrict__ aux, unsigned short* __restrict__ obf,
    float* __restrict__ of, unsigned short* __restrict__ vtb, int K, int Ndim,
    float* __restrict__ q2o, float* __restrict__ k2o) {
  __shared__ __align__(16) unsigned short As[128 * 64];
  __shared__ __align__(16) unsigned short Bs[BN * 64];
  const int tid = threadIdx.x, lane = tid & 63, wave = tid >> 6;
  const int wr = wave >> 1, wc = wave & 1;
  constexpr int NI  = (BN == 128) ? 4 : (BN == 64 ? 2 : 1);
  constexpr int WCW = (BN == 128) ? 64 : (BN == 64 ? 32 : 16);
  const int nwg = gridDim.x * gridDim.y;
  const int orig = blockIdx.y * gridDim.x + blockIdx.x;
  const int swz = (orig & 7) * (nwg >> 3) + (orig >> 3);
  const int m0 = (swz / gridDim.x) * 128, n0 = (swz % gridDim.x) * BN;
  f32x4 acc[4][NI] = {};
  for (int k0 = 0; k0 < K; k0 += 64) {
    __syncthreads();
    #pragma unroll
    for (int p = 0; p < 4; p++) {
      const int o = p * 4096 + tid * 16;
      const int row = o >> 7, c8 = (o >> 4) & 7;
      gload_lds16(A + (size_t)(m0 + row) * K + k0 + c8 * 8, (char*)As + o);
    }
    #pragma unroll
    for (int p = 0; p < BN / 32; p++) {
      const int o = p * 4096 + tid * 16;
      const int row = o >> 7, c8 = (o >> 4) & 7;
      gload_lds16(BT + (size_t)(n0 + row) * K + k0 + c8 * 8, (char*)Bs + o);
    }
    __syncthreads();
    #pragma unroll
    for (int ks = 0; ks < 2; ks++) {
      short8 af[4], bfr[NI];
      #pragma unroll
      for (int i = 0; i < 4; i++)
        af[i] = *(const short8*)&As[(wr * 64 + i * 16 + (lane & 15)) * 64 + ks * 32 + (lane >> 4) * 8];
      #pragma unroll
      for (int i = 0; i < NI; i++)
        bfr[i] = *(const short8*)&Bs[(wc * WCW + i * 16 + (lane & 15)) * 64 + ks * 32 + (lane >> 4) * 8];
      #pragma unroll
      for (int mi = 0; mi < 4; mi++)
        #pragma unroll
        for (int ni = 0; ni < NI; ni++)
          acc[mi][ni] = __builtin_amdgcn_mfma_f32_16x16x32_bf16(af[mi], bfr[ni], acc[mi][ni], 0, 0, 0);
    }
  }
  const int rbase = m0 + wr * 64 + ((lane >> 4) << 2);
  const int cb = n0 + wc * WCW + (lane & 15);
  float rowsum[4][4];   // [mi][j] — only used by EPI 0 q/k blocks
  if (EPI == 0) {
    #pragma unroll
    for (int mi = 0; mi < 4; mi++)
      #pragma unroll
      for (int j = 0; j < 4; j++) rowsum[mi][j] = 0.f;
  }
  float sL = 0.f, ssL = 0.f, sH = 0.f, ssH = 0.f;   // EPI 3 stats partials
  #pragma unroll
  for (int mi = 0; mi < 4; mi++) {
    #pragma unroll
    for (int ni = 0; ni < NI; ni++) {
      const int col = cb + ni * 16;
      const float bv = bias[col];
      const int r0_ = rbase + mi * 16;
      if (EPI == 0) {
        if (col < 1024) {
          #pragma unroll
          for (int j = 0; j < 4; j++) {
            unsigned short u = f2bf(acc[mi][ni][j] + bv);
            obf[(size_t)(r0_ + j) * 1024 + col] = u;
            float vb = bf2f(u);
            rowsum[mi][j] += vb * vb;
          }
        } else {
          const int hh = (col - 1024) >> 8, cc = (col - 1024) & 255;
          const int b_ = r0_ >> 10, nb = r0_ & (Nn - 1);
          ushort4 pk;
          unsigned short* pp = (unsigned short*)&pk;
          #pragma unroll
          for (int j = 0; j < 4; j++) pp[j] = f2bf(acc[mi][ni][j] + bv);
          *(ushort4*)&vtb[((size_t)((b_ * 8 + hh) * 256 + cc)) * 1024 + nb] = pk;
        }
      } else if (EPI == 1) {
        #pragma unroll
        for (int j = 0; j < 4; j++) {
          size_t o = (size_t)(r0_ + j) * Ndim + col;
          of[o] = acc[mi][ni][j] + bv + res[o];
        }
      } else if (EPI == 3) {
        #pragma unroll
        for (int j = 0; j < 4; j++) {
          size_t o = (size_t)(r0_ + j) * Ndim + col;
          float val = acc[mi][ni][j] + bv + res[o];
          of[o] = val;
          if (mi < 2) { sL += val; ssL += val * val; }
          else        { sH += val; ssH += val * val; }
        }
      } else {
        const int b_ = r0_ >> 10;
        const float sg = aux[b_ * 1024 + col];
        #pragma unroll
        for (int j = 0; j < 4; j++) {
          float g = (acc[mi][ni][j] + bv) * sg;
          obf[(size_t)(r0_ + j) * Ndim + col] = f2bf(g / (1.f + __expf(-g)));
        }
      }
    }
  }
  // Fused q2/k2: this wave's 64-col chunk is one head's q or k slice.
  if (EPI == 0) {
    const int chunk64 = n0 + wc * 64;
    if (chunk64 < 1024) {
      const int chunk = chunk64 >> 6;               // 0..15
      float* dst = (chunk < 8) ? q2o : k2o;
      const int h = chunk & 7;
      #pragma unroll
      for (int mi = 0; mi < 4; mi++) {
        #pragma unroll
        for (int j = 0; j < 4; j++) {
          float s = rowsum[mi][j];
          s += __shfl_xor(s, 1);
          s += __shfl_xor(s, 2);
          s += __shfl_xor(s, 4);
          s += __shfl_xor(s, 8);
          if ((lane & 15) == 0) {
            const int row = rbase + mi * 16 + j;
            dst[(size_t)((row >> 10) * 8 + h) * 1024 + (row & 1023)] = s;
          }
        }
      }
    }
  }
  // Fused seq-stats partials (EPI 3, BN=32): write [b][chunk][2][256] partials.
  if (EPI == 3) {
    sL  += __shfl_xor(sL, 16);  sL  += __shfl_xor(sL, 32);
    ssL += __shfl_xor(ssL, 16); ssL += __shfl_xor(ssL, 32);
    sH  += __shfl_xor(sH, 16);  sH  += __shfl_xor(sH, 32);
    ssH += __shfl_xor(ssH, 16); ssH += __shfl_xor(ssH, 32);
    if (lane < 16) {
      const int b_ = m0 >> 10;
      const int cL = ((m0 & 1023) >> 5) + wr * 2;
      const int d  = cb;
      q2o[((size_t)(b_ * 32 + cL) * 2) * 256 + d]       = sL;
      q2o[((size_t)(b_ * 32 + cL) * 2) * 256 + 256 + d] = ssL;
      q2o[((size_t)(b_ * 32 + cL + 1) * 2) * 256 + d]       = sH;
      q2o[((size_t)(b_ * 32 + cL + 1) * 2) * 256 + 256 + d] = ssH;
    }
  }
}

// ---------------- Gaussian-kernel attention v3 (round-6/12 PROVEN source, FROZEN) ----------------
__global__ __launch_bounds__(512, 2) void attn3(
    const unsigned short* __restrict__ qk, const unsigned short* __restrict__ vt,
    const float* __restrict__ q2g, const float* __restrict__ k2g,
    unsigned short* __restrict__ aout, const float* __restrict__ scale_p) {
  const int dd = blockIdx.x;
  const int bh = (dd & 7) + ((dd >> 5) << 3);   // 4 q-tiles of one bh -> same XCD
  const int qt = (dd >> 3) & 3;
  const int b = bh >> 3, h = bh & 7;
  const float sc = scale_p[0];
  const float inv_s2 = 1.f / (sc * sc);

  __shared__ __align__(16) unsigned short Ks[2][64 * 64];
  __shared__ __align__(16) unsigned short Vs[2][256 * 64];

  const int tid = threadIdx.x, lane = tid & 63, wave = tid >> 6;
  const int l31 = lane & 31, lh = lane >> 5;
  const int qr0 = qt * 256 + wave * 32;

  auto stage = [&](int kt, int buf) {
    { // K tile 8 KiB (inverse-swizzled global source, linear LDS dest)
      const int row = tid >> 3;
      const int c8 = (tid & 7) ^ (row & 7);
      gload_lds16(qk + (size_t)(b * 1024 + kt * 64 + row) * 1024 + 512 + h * 64 + c8 * 8,
                  (char*)&Ks[buf][0] + tid * 16);
    }
    #pragma unroll
    for (int p = 0; p < 4; p++) { // V tile 32 KiB
      const int o = p * 8192 + tid * 16;
      const int row = o >> 7;
      const int c8 = ((o >> 4) & 7) ^ (row & 7);
      gload_lds16(vt + (size_t)(bh * 256 + row) * 1024 + kt * 64 + c8 * 8,
                  (char*)&Vs[buf][0] + o);
    }
  };

  stage(0, 0);

  // Q B-frags + q2, direct from global (once per block)
  short8 qfrag[4];
  const unsigned short* qbase = qk + (size_t)(b * 1024 + qr0 + l31) * 1024 + h * 64;
  #pragma unroll
  for (int ks = 0; ks < 4; ks++)
    qfrag[ks] = *(const short8*)(qbase + ks * 16 + lh * 8);
  const float q2v = q2g[(size_t)bh * 1024 + qr0 + l31];

  f32x16 acc[8] = {};
  __syncthreads();   // prologue stage visible

  for (int kt = 0; kt < 16; kt++) {
    const int cur = kt & 1;
    if (kt < 15) stage(kt + 1, cur ^ 1);   // in flight until the barrier

    uint4 pa[4];   // P A-frags, [k-16-slice] x 4 words
    #pragma unroll
    for (int mi = 0; mi < 2; mi++) {
      // S^T = mfma(K, Q): D[k_local][q], k rows mi*32..+31 of this tile
      f32x16 sacc = {};
      #pragma unroll
      for (int ks = 0; ks < 4; ks++) {
        const int row = mi * 32 + l31;
        const int sl = (ks * 2 + lh) ^ (row & 7);
        short8 kf = *(const short8*)((const char*)&Ks[cur][0] + row * 128 + sl * 16);
        sacc = __builtin_amdgcn_mfma_f32_32x32x16_bf16(kf, qfrag[ks], sacc, 0, 0, 0);
      }
      // d2 -> exp, all registers; k2 via broadcast global float4
      const float* k2p = k2g + (size_t)bh * 1024 + kt * 64 + mi * 32 + lh * 4;
      float pr[16];
      #pragma unroll
      for (int g = 0; g < 4; g++) {
        const float4 k2v = *(const float4*)(k2p + g * 8);
        #pragma unroll
        for (int j = 0; j < 4; j++) {
          float d2 = q2v + ((const float*)&k2v)[j] - 2.f * sacc[g * 4 + j];
          pr[g * 4 + j] = __expf(-fmaxf(d2, 0.f) * inv_s2);
        }
      }
      // pack to bf16 A-frags: 8 cvt_pk + 4 permlane32_swap per mi.
      // permlane32_swap(w0,w2): w0'={w0.lo,w2.lo}=word0, w2'={w0.hi,w2.hi}=word2.
      #pragma unroll
      for (int ksh = 0; ksh < 2; ksh++) {
        unsigned w0, w1, w2, w3;
        const int o = ksh * 8;
        asm("v_cvt_pk_bf16_f32 %0, %1, %2" : "=v"(w0) : "v"(pr[o + 0]), "v"(pr[o + 1]));
        asm("v_cvt_pk_bf16_f32 %0, %1, %2" : "=v"(w1) : "v"(pr[o + 2]), "v"(pr[o + 3]));
        asm("v_cvt_pk_bf16_f32 %0, %1, %2" : "=v"(w2) : "v"(pr[o + 4]), "v"(pr[o + 5]));
        asm("v_cvt_pk_bf16_f32 %0, %1, %2" : "=v"(w3) : "v"(pr[o + 6]), "v"(pr[o + 7]));
        asm("v_permlane32_swap_b32 %0, %1" : "+v"(w0), "+v"(w2));
        asm("v_permlane32_swap_b32 %0, %1" : "+v"(w1), "+v"(w3));
        pa[mi * 2 + ksh] = make_uint4(w0, w1, w2, w3);
      }
    }
    // PV: acc[ci] += P(32q x 64k) @ V(64k x 256c), V from swizzled LDS
    #pragma unroll
    for (int ci = 0; ci < 8; ci++) {
      #pragma unroll
      for (int ks = 0; ks < 4; ks++) {
        const int row = ci * 32 + l31;
        const int sl = (ks * 2 + lh) ^ (row & 7);
        short8 vf = *(const short8*)((const char*)&Vs[cur][0] + row * 128 + sl * 16);
        short8 paf = *(const short8*)&pa[ks];
        acc[ci] = __builtin_amdgcn_mfma_f32_32x32x16_bf16(paf, vf, acc[ci], 0, 0, 0);
      }
    }
    __syncthreads();   // cur reads done; stage(kt+1) drained (vmcnt0 at barrier)
  }

  const size_t row0 = (size_t)(b * 1024 + qr0);
  #pragma unroll
  for (int ci = 0; ci < 8; ci++) {
    #pragma unroll
    for (int r = 0; r < 16; r++) {
      const int q = (r & 3) + 8 * (r >> 2) + 4 * lh;
      aout[(row0 + q) * 2048 + h * 256 + ci * 32 + l31] = f2bf(acc[ci][r]);
    }
  }
}

extern "C" void kernel_launch(void* const* d_in, const int* in_sizes, int n_in,
                              void* d_out, int out_size, void* d_ws, size_t ws_size,
                              hipStream_t stream) {
  (void)in_sizes; (void)n_in; (void)out_size; (void)ws_size;
  const float* x      = (const float*)d_in[0];
  const float* t      = (const float*)d_in[1];
  const float* gamma  = (const float*)d_in[2];
  const float* beta   = (const float*)d_in[3];
  const float* pos    = (const float*)d_in[4];
  const float* Wqkv   = (const float*)d_in[5];
  const float* bqkv   = (const float*)d_in[6];
  const float* Wm     = (const float*)d_in[7];
  const float* bm     = (const float*)d_in[8];
  const float* Wt     = (const float*)d_in[9];
  const float* bt     = (const float*)d_in[10];
  const float* gamma1 = (const float*)d_in[11];
  const float* beta1  = (const float*)d_in[12];
  const float* Wf1    = (const float*)d_in[13];
  const float* bf1    = (const float*)d_in[14];
  const float* Wf2    = (const float*)d_in[15];
  const float* bf2    = (const float*)d_in[16];
  const float* scale  = (const float*)d_in[17];
  float* out = (float*)d_out;

  char* ws = (char*)d_ws;
  size_t off = 0;
  auto alloc = [&](size_t bytes) -> void* {
    void* p = ws + off;
    off += (bytes + 255) & ~(size_t)255;
    return p;
  };
  unsigned short* qkb   = (unsigned short*)alloc((size_t)8192 * 1024 * 2);
  unsigned short* vtb   = (unsigned short*)alloc((size_t)64 * 256 * 1024 * 2);
  unsigned short* aoutb = (unsigned short*)alloc((size_t)8192 * 2048 * 2);
  unsigned short* hbuf  = (unsigned short*)alloc((size_t)8192 * 256 * 2);
  unsigned short* ffbuf = (unsigned short*)alloc((size_t)8192 * 1024 * 2);
  float* x1             = (float*)alloc((size_t)8192 * 256 * 4);
  unsigned short* WqkvT = (unsigned short*)alloc((size_t)3072 * 256 * 2);
  unsigned short* WmT   = (unsigned short*)alloc((size_t)256 * 2048 * 2);
  unsigned short* Wf1T  = (unsigned short*)alloc((size_t)1024 * 256 * 2);
  unsigned short* Wf2T  = (unsigned short*)alloc((size_t)256 * 1024 * 2);
  float* partial = (float*)alloc((size_t)8 * 32 * 2 * 256 * 4);
  float* mean1   = (float*)alloc(8 * 256 * 4);
  float* rstd1   = (float*)alloc(8 * 256 * 4);
  float* mean2   = (float*)alloc(8 * 256 * 4);
  float* rstd2   = (float*)alloc(8 * 256 * 4);
  float* sig_ts  = (float*)alloc(8 * 1024 * 4);
  float* q2g     = (float*)alloc((size_t)64 * 1024 * 4);
  float* k2g     = (float*)alloc((size_t)64 * 1024 * 4);

  transpose4<<<1824, 256, 0, stream>>>(Wqkv, WqkvT, Wm, WmT, Wf1, Wf1T, Wf2, Wf2T,
                                       t, Wt, bt, sig_ts);

  stats_pass1<<<256, 256, 0, stream>>>(x, partial);
  stats_pass2<<<8, 256, 0, stream>>>(partial, mean1, rstd1);
  norm_swish<true><<<2048, 256, 0, stream>>>(x, mean1, rstd1, gamma, beta, pos, hbuf);

  gemm2<0, 128><<<dim3(24, 64), 256, 0, stream>>>(hbuf, WqkvT, bqkv, nullptr, nullptr,
                                                  qkb, nullptr, vtb, 256, 3072, q2g, k2g);
  attn3<<<256, 512, 0, stream>>>(qkb, vtb, q2g, k2g, aoutb, scale);
  // Wm GEMM: EPI 3 writes x1 AND the seq-stats partials (deletes stats_pass1(x1))
  gemm2<3, 32><<<dim3(8, 64), 256, 0, stream>>>(aoutb, WmT, bm, x, nullptr,
                                                nullptr, x1, nullptr, 2048, 256,
                                                partial, nullptr);

  stats_pass2<<<8, 256, 0, stream>>>(partial, mean2, rstd2);
  norm_swish<false><<<2048, 256, 0, stream>>>(x1, mean2, rstd2, gamma1, beta1, nullptr, hbuf);

  gemm2<2, 128><<<dim3(8, 64), 256, 0, stream>>>(hbuf, Wf1T, bf1, nullptr, sig_ts,
                                                 ffbuf, nullptr, nullptr, 256, 1024,
                                                 nullptr, nullptr);
  gemm2<1, 32><<<dim3(8, 64), 256, 0, stream>>>(ffbuf, Wf2T, bf2, x1, nullptr,
                                                nullptr, out, nullptr, 1024, 256,
                                                nullptr, nullptr);
}

// Round 21
// 179.379 us; speedup vs baseline: 1.1708x; 1.0092x over previous
//
#include <hip/hip_runtime.h>
#include <math.h>

typedef __attribute__((ext_vector_type(4))) float f32x4;
typedef __attribute__((ext_vector_type(16))) float f32x16;
typedef __attribute__((ext_vector_type(8))) short short8;

#define DI __device__ __forceinline__

static constexpr int Bb = 8;
static constexpr int Nn = 1024;
static constexpr int Dd = 256;

DI unsigned short f2bf(float f) {
  union { float f; unsigned u; } v; v.f = f;
  unsigned r = v.u + 0x7fffu + ((v.u >> 16) & 1u);
  return (unsigned short)(r >> 16);
}
DI float bf2f(unsigned short h) {
  union { unsigned u; float f; } v; v.u = ((unsigned)h) << 16; return v.f;
}

DI void gload_lds16(const void* g, void* l) {
  __builtin_amdgcn_global_load_lds((const __attribute__((address_space(1))) unsigned int*)g,
                                   (__attribute__((address_space(3))) unsigned int*)l, 16, 0, 0);
}

// ---------------- stats pass 2 (reduce partials -> mean/rstd) ----------------
__global__ void stats_pass2(const float* __restrict__ partial, float* __restrict__ mean,
                            float* __restrict__ rstd) {
  int d = threadIdx.x; int b = blockIdx.x;
  float s = 0.f, ss = 0.f;
  for (int c = 0; c < 32; c++) {
    s  += partial[((size_t)(b * 32 + c) * 2) * Dd + d];
    ss += partial[((size_t)(b * 32 + c) * 2) * Dd + Dd + d];
  }
  float m = s * (1.f / Nn);
  float var = ss * (1.f / Nn) - m * m;
  mean[b * Dd + d] = m;
  rstd[b * Dd + d] = rsqrtf(var + 1e-5f);
}

// ---------------- norm (+pos) + swish -> bf16 ----------------
template<bool POS>
__global__ void norm_swish(const float* __restrict__ x, const float* __restrict__ mean,
                           const float* __restrict__ rstd, const float* __restrict__ gamma,
                           const float* __restrict__ beta, const float* __restrict__ pos,
                           unsigned short* __restrict__ out) {
  size_t idx = ((size_t)blockIdx.x * 256 + threadIdx.x) * 4;
  int d = (int)(idx & (Dd - 1));
  size_t row = idx >> 8;
  int b = (int)(row >> 10);
  int n = (int)(row & (Nn - 1));
  const float4 xv = *(const float4*)(x + idx);
  const float4 gv = *(const float4*)(gamma + d);
  const float4 bv = *(const float4*)(beta + d);
  const float4 mv = *(const float4*)(mean + b * Dd + d);
  const float4 rv = *(const float4*)(rstd + b * Dd + d);
  float v[4]  = {xv.x, xv.y, xv.z, xv.w};
  float g[4]  = {gv.x, gv.y, gv.z, gv.w};
  float be[4] = {bv.x, bv.y, bv.z, bv.w};
  float mm[4] = {mv.x, mv.y, mv.z, mv.w};
  float rr[4] = {rv.x, rv.y, rv.z, rv.w};
  float pp[4] = {0.f, 0.f, 0.f, 0.f};
  if (POS) {
    const float4 pv = *(const float4*)(pos + (size_t)n * Dd + d);
    pp[0] = pv.x; pp[1] = pv.y; pp[2] = pv.z; pp[3] = pv.w;
  }
  ushort4 o;
  unsigned short* op = (unsigned short*)&o;
  #pragma unroll
  for (int j = 0; j < 4; j++) {
    float val = (v[j] - mm[j]) * rr[j] * g[j] + be[j];
    if (POS) val += pp[j];
    float sw = val / (1.f + __expf(-val));
    op[j] = f2bf(sw);
  }
  *(ushort4*)(out + idx) = o;
}

// ---------------- fused weight transposes + time projection + stats_pass1(x) ----------------
// transpose_tile EXONERATED (R8/R14 bit-identical evidence).
DI void transpose_tile(const float* in, unsigned short* out, int R, int C,
                       int bx, int by) {
  __shared__ float tile[32][33];
  int c0 = bx * 32, r0 = by * 32;
  int tx = threadIdx.x & 31, ty = threadIdx.x >> 5;
  for (int i = ty; i < 32; i += 8)
    tile[i][tx] = in[(size_t)(r0 + i) * C + c0 + tx];
  __syncthreads();
  for (int i = ty; i < 32; i += 8)
    out[(size_t)(c0 + i) * R + r0 + tx] = f2bf(tile[tx][i]);
}

// grid: [0,768) Wqkv 256x3072 (96x8); [768,1280) Wm 2048x256 (8x64);
//       [1280,1536) Wf1 256x1024 (32x8); [1536,1792) Wf2 1024x256 (8x32);
//       [1792,1824) time_proj (32 blocks); [1824,2080) stats_pass1(x) (256 blocks)
__global__ void transpose4(const float* __restrict__ w0, unsigned short* __restrict__ o0,
                           const float* __restrict__ w1, unsigned short* __restrict__ o1,
                           const float* __restrict__ w2, unsigned short* __restrict__ o2,
                           const float* __restrict__ w3, unsigned short* __restrict__ o3,
                           const float* __restrict__ t, const float* __restrict__ Wt,
                           const float* __restrict__ bt, float* __restrict__ sig_ts,
                           const float* __restrict__ x, float* __restrict__ partial) {
  int g = blockIdx.x;
  if (g < 768)        transpose_tile(w0, o0, 256, 3072, g % 96, g / 96);
  else if (g < 1280)  { g -= 768;  transpose_tile(w1, o1, 2048, 256, g % 8, g / 8); }
  else if (g < 1536)  { g -= 1280; transpose_tile(w2, o2, 256, 1024, g % 32, g / 32); }
  else if (g < 1792)  { g -= 1536; transpose_tile(w3, o3, 1024, 256, g % 8, g / 8); }
  else if (g < 1824) {
    g -= 1792;
    const int j = (g & 3) * 256 + threadIdx.x;   // 0..1023
    const int b = g >> 2;                        // 0..7
    const float* tb = t + b * 256;
    float acc = bt[256 + j];
    for (int k = 0; k < 256; k++) acc += tb[k] * Wt[k * 1280 + 256 + j];
    sig_ts[b * 1024 + j] = 1.f / (1.f + __expf(-acc));
  } else {
    g -= 1824;                                   // stats_pass1(x): 0..255
    const int d = threadIdx.x;
    const int b = g >> 5;
    const int c = g & 31;
    const float* p = x + ((size_t)b * Nn + c * 32) * Dd + d;
    float s = 0.f, ss = 0.f;
    for (int i = 0; i < 32; i++) { float v = p[(size_t)i * Dd]; s += v; ss += v * v; }
    float* o = partial + ((size_t)(b * 32 + c) * 2) * Dd + d;
    o[0] = s; o[Dd] = ss;
  }
}

// ---------------- GEMM (m97-style: linear LDS + global_load_lds) ----------------
// T1 XCD swizzle (validated R12). BN parametric {128,64,32}.
// EPI 0: qkv split epilogue + FUSED q2/k2 row-sum reduction.
// EPI 1: f32 out = acc+bias+res.
// EPI 2: gated swish -> bf16.
// EPI 3: EPI 1 + FUSED seq-stats partials (BN=32 only).
template<int EPI, int BN>
__global__ __launch_bounds__(256, 3) void gemm2(
    const unsigned short* __restrict__ A, const unsigned short* __restrict__ BT,
    const float* __restrict__ bias, const float* __restrict__ res,
    const float* __restrict__ aux, unsigned short* __restrict__ obf,
    float* __restrict__ of, unsigned short* __restrict__ vtb, int K, int Ndim,
    float* __restrict__ q2o, float* __restrict__ k2o) {
  __shared__ __align__(16) unsigned short As[128 * 64];
  __shared__ __align__(16) unsigned short Bs[BN * 64];
  const int tid = threadIdx.x, lane = tid & 63, wave = tid >> 6;
  const int wr = wave >> 1, wc = wave & 1;
  constexpr int NI  = (BN == 128) ? 4 : (BN == 64 ? 2 : 1);
  constexpr int WCW = (BN == 128) ? 64 : (BN == 64 ? 32 : 16);
  const int nwg = gridDim.x * gridDim.y;
  const int orig = blockIdx.y * gridDim.x + blockIdx.x;
  const int swz = (orig & 7) * (nwg >> 3) + (orig >> 3);
  const int m0 = (swz / gridDim.x) * 128, n0 = (swz % gridDim.x) * BN;
  f32x4 acc[4][NI] = {};
  for (int k0 = 0; k0 < K; k0 += 64) {
    __syncthreads();
    #pragma unroll
    for (int p = 0; p < 4; p++) {
      const int o = p * 4096 + tid * 16;
      const int row = o >> 7, c8 = (o >> 4) & 7;
      gload_lds16(A + (size_t)(m0 + row) * K + k0 + c8 * 8, (char*)As + o);
    }
    #pragma unroll
    for (int p = 0; p < BN / 32; p++) {
      const int o = p * 4096 + tid * 16;
      const int row = o >> 7, c8 = (o >> 4) & 7;
      gload_lds16(BT + (size_t)(n0 + row) * K + k0 + c8 * 8, (char*)Bs + o);
    }
    __syncthreads();
    #pragma unroll
    for (int ks = 0; ks < 2; ks++) {
      short8 af[4], bfr[NI];
      #pragma unroll
      for (int i = 0; i < 4; i++)
        af[i] = *(const short8*)&As[(wr * 64 + i * 16 + (lane & 15)) * 64 + ks * 32 + (lane >> 4) * 8];
      #pragma unroll
      for (int i = 0; i < NI; i++)
        bfr[i] = *(const short8*)&Bs[(wc * WCW + i * 16 + (lane & 15)) * 64 + ks * 32 + (lane >> 4) * 8];
      #pragma unroll
      for (int mi = 0; mi < 4; mi++)
        #pragma unroll
        for (int ni = 0; ni < NI; ni++)
          acc[mi][ni] = __builtin_amdgcn_mfma_f32_16x16x32_bf16(af[mi], bfr[ni], acc[mi][ni], 0, 0, 0);
    }
  }
  const int rbase = m0 + wr * 64 + ((lane >> 4) << 2);
  const int cb = n0 + wc * WCW + (lane & 15);
  float rowsum[4][4];   // [mi][j] — only used by EPI 0 q/k blocks
  if (EPI == 0) {
    #pragma unroll
    for (int mi = 0; mi < 4; mi++)
      #pragma unroll
      for (int j = 0; j < 4; j++) rowsum[mi][j] = 0.f;
  }
  float sL = 0.f, ssL = 0.f, sH = 0.f, ssH = 0.f;   // EPI 3 stats partials
  #pragma unroll
  for (int mi = 0; mi < 4; mi++) {
    #pragma unroll
    for (int ni = 0; ni < NI; ni++) {
      const int col = cb + ni * 16;
      const float bv = bias[col];
      const int r0_ = rbase + mi * 16;
      if (EPI == 0) {
        if (col < 1024) {
          #pragma unroll
          for (int j = 0; j < 4; j++) {
            unsigned short u = f2bf(acc[mi][ni][j] + bv);
            obf[(size_t)(r0_ + j) * 1024 + col] = u;
            float vb = bf2f(u);
            rowsum[mi][j] += vb * vb;
          }
        } else {
          const int hh = (col - 1024) >> 8, cc = (col - 1024) & 255;
          const int b_ = r0_ >> 10, nb = r0_ & (Nn - 1);
          ushort4 pk;
          unsigned short* pp = (unsigned short*)&pk;
          #pragma unroll
          for (int j = 0; j < 4; j++) pp[j] = f2bf(acc[mi][ni][j] + bv);
          *(ushort4*)&vtb[((size_t)((b_ * 8 + hh) * 256 + cc)) * 1024 + nb] = pk;
        }
      } else if (EPI == 1) {
        #pragma unroll
        for (int j = 0; j < 4; j++) {
          size_t o = (size_t)(r0_ + j) * Ndim + col;
          of[o] = acc[mi][ni][j] + bv + res[o];
        }
      } else if (EPI == 3) {
        #pragma unroll
        for (int j = 0; j < 4; j++) {
          size_t o = (size_t)(r0_ + j) * Ndim + col;
          float val = acc[mi][ni][j] + bv + res[o];
          of[o] = val;
          if (mi < 2) { sL += val; ssL += val * val; }
          else        { sH += val; ssH += val * val; }
        }
      } else {
        const int b_ = r0_ >> 10;
        const float sg = aux[b_ * 1024 + col];
        #pragma unroll
        for (int j = 0; j < 4; j++) {
          float g = (acc[mi][ni][j] + bv) * sg;
          obf[(size_t)(r0_ + j) * Ndim + col] = f2bf(g / (1.f + __expf(-g)));
        }
      }
    }
  }
  // Fused q2/k2: this wave's 64-col chunk is one head's q or k slice.
  if (EPI == 0) {
    const int chunk64 = n0 + wc * 64;
    if (chunk64 < 1024) {
      const int chunk = chunk64 >> 6;               // 0..15
      float* dst = (chunk < 8) ? q2o : k2o;
      const int h = chunk & 7;
      #pragma unroll
      for (int mi = 0; mi < 4; mi++) {
        #pragma unroll
        for (int j = 0; j < 4; j++) {
          float s = rowsum[mi][j];
          s += __shfl_xor(s, 1);
          s += __shfl_xor(s, 2);
          s += __shfl_xor(s, 4);
          s += __shfl_xor(s, 8);
          if ((lane & 15) == 0) {
            const int row = rbase + mi * 16 + j;
            dst[(size_t)((row >> 10) * 8 + h) * 1024 + (row & 1023)] = s;
          }
        }
      }
    }
  }
  // Fused seq-stats partials (EPI 3, BN=32): write [b][chunk][2][256] partials.
  if (EPI == 3) {
    sL  += __shfl_xor(sL, 16);  sL  += __shfl_xor(sL, 32);
    ssL += __shfl_xor(ssL, 16); ssL += __shfl_xor(ssL, 32);
    sH  += __shfl_xor(sH, 16);  sH  += __shfl_xor(sH, 32);
    ssH += __shfl_xor(ssH, 16); ssH += __shfl_xor(ssH, 32);
    if (lane < 16) {
      const int b_ = m0 >> 10;
      const int cL = ((m0 & 1023) >> 5) + wr * 2;
      const int d  = cb;
      q2o[((size_t)(b_ * 32 + cL) * 2) * 256 + d]       = sL;
      q2o[((size_t)(b_ * 32 + cL) * 2) * 256 + 256 + d] = ssL;
      q2o[((size_t)(b_ * 32 + cL + 1) * 2) * 256 + d]       = sH;
      q2o[((size_t)(b_ * 32 + cL + 1) * 2) * 256 + 256 + d] = ssH;
    }
  }
}

// ---------------- Gaussian-kernel attention v3 (round-6/12 PROVEN source, FROZEN) ----------------
__global__ __launch_bounds__(512, 2) void attn3(
    const unsigned short* __restrict__ qk, const unsigned short* __restrict__ vt,
    const float* __restrict__ q2g, const float* __restrict__ k2g,
    unsigned short* __restrict__ aout, const float* __restrict__ scale_p) {
  const int dd = blockIdx.x;
  const int bh = (dd & 7) + ((dd >> 5) << 3);   // 4 q-tiles of one bh -> same XCD
  const int qt = (dd >> 3) & 3;
  const int b = bh >> 3, h = bh & 7;
  const float sc = scale_p[0];
  const float inv_s2 = 1.f / (sc * sc);

  __shared__ __align__(16) unsigned short Ks[2][64 * 64];
  __shared__ __align__(16) unsigned short Vs[2][256 * 64];

  const int tid = threadIdx.x, lane = tid & 63, wave = tid >> 6;
  const int l31 = lane & 31, lh = lane >> 5;
  const int qr0 = qt * 256 + wave * 32;

  auto stage = [&](int kt, int buf) {
    { // K tile 8 KiB (inverse-swizzled global source, linear LDS dest)
      const int row = tid >> 3;
      const int c8 = (tid & 7) ^ (row & 7);
      gload_lds16(qk + (size_t)(b * 1024 + kt * 64 + row) * 1024 + 512 + h * 64 + c8 * 8,
                  (char*)&Ks[buf][0] + tid * 16);
    }
    #pragma unroll
    for (int p = 0; p < 4; p++) { // V tile 32 KiB
      const int o = p * 8192 + tid * 16;
      const int row = o >> 7;
      const int c8 = ((o >> 4) & 7) ^ (row & 7);
      gload_lds16(vt + (size_t)(bh * 256 + row) * 1024 + kt * 64 + c8 * 8,
                  (char*)&Vs[buf][0] + o);
    }
  };

  stage(0, 0);

  // Q B-frags + q2, direct from global (once per block)
  short8 qfrag[4];
  const unsigned short* qbase = qk + (size_t)(b * 1024 + qr0 + l31) * 1024 + h * 64;
  #pragma unroll
  for (int ks = 0; ks < 4; ks++)
    qfrag[ks] = *(const short8*)(qbase + ks * 16 + lh * 8);
  const float q2v = q2g[(size_t)bh * 1024 + qr0 + l31];

  f32x16 acc[8] = {};
  __syncthreads();   // prologue stage visible

  for (int kt = 0; kt < 16; kt++) {
    const int cur = kt & 1;
    if (kt < 15) stage(kt + 1, cur ^ 1);   // in flight until the barrier

    uint4 pa[4];   // P A-frags, [k-16-slice] x 4 words
    #pragma unroll
    for (int mi = 0; mi < 2; mi++) {
      // S^T = mfma(K, Q): D[k_local][q], k rows mi*32..+31 of this tile
      f32x16 sacc = {};
      #pragma unroll
      for (int ks = 0; ks < 4; ks++) {
        const int row = mi * 32 + l31;
        const int sl = (ks * 2 + lh) ^ (row & 7);
        short8 kf = *(const short8*)((const char*)&Ks[cur][0] + row * 128 + sl * 16);
        sacc = __builtin_amdgcn_mfma_f32_32x32x16_bf16(kf, qfrag[ks], sacc, 0, 0, 0);
      }
      // d2 -> exp, all registers; k2 via broadcast global float4
      const float* k2p = k2g + (size_t)bh * 1024 + kt * 64 + mi * 32 + lh * 4;
      float pr[16];
      #pragma unroll
      for (int g = 0; g < 4; g++) {
        const float4 k2v = *(const float4*)(k2p + g * 8);
        #pragma unroll
        for (int j = 0; j < 4; j++) {
          float d2 = q2v + ((const float*)&k2v)[j] - 2.f * sacc[g * 4 + j];
          pr[g * 4 + j] = __expf(-fmaxf(d2, 0.f) * inv_s2);
        }
      }
      // pack to bf16 A-frags: 8 cvt_pk + 4 permlane32_swap per mi.
      // permlane32_swap(w0,w2): w0'={w0.lo,w2.lo}=word0, w2'={w0.hi,w2.hi}=word2.
      #pragma unroll
      for (int ksh = 0; ksh < 2; ksh++) {
        unsigned w0, w1, w2, w3;
        const int o = ksh * 8;
        asm("v_cvt_pk_bf16_f32 %0, %1, %2" : "=v"(w0) : "v"(pr[o + 0]), "v"(pr[o + 1]));
        asm("v_cvt_pk_bf16_f32 %0, %1, %2" : "=v"(w1) : "v"(pr[o + 2]), "v"(pr[o + 3]));
        asm("v_cvt_pk_bf16_f32 %0, %1, %2" : "=v"(w2) : "v"(pr[o + 4]), "v"(pr[o + 5]));
        asm("v_cvt_pk_bf16_f32 %0, %1, %2" : "=v"(w3) : "v"(pr[o + 6]), "v"(pr[o + 7]));
        asm("v_permlane32_swap_b32 %0, %1" : "+v"(w0), "+v"(w2));
        asm("v_permlane32_swap_b32 %0, %1" : "+v"(w1), "+v"(w3));
        pa[mi * 2 + ksh] = make_uint4(w0, w1, w2, w3);
      }
    }
    // PV: acc[ci] += P(32q x 64k) @ V(64k x 256c), V from swizzled LDS
    #pragma unroll
    for (int ci = 0; ci < 8; ci++) {
      #pragma unroll
      for (int ks = 0; ks < 4; ks++) {
        const int row = ci * 32 + l31;
        const int sl = (ks * 2 + lh) ^ (row & 7);
        short8 vf = *(const short8*)((const char*)&Vs[cur][0] + row * 128 + sl * 16);
        short8 paf = *(const short8*)&pa[ks];
        acc[ci] = __builtin_amdgcn_mfma_f32_32x32x16_bf16(paf, vf, acc[ci], 0, 0, 0);
      }
    }
    __syncthreads();   // cur reads done; stage(kt+1) drained (vmcnt0 at barrier)
  }

  const size_t row0 = (size_t)(b * 1024 + qr0);
  #pragma unroll
  for (int ci = 0; ci < 8; ci++) {
    #pragma unroll
    for (int r = 0; r < 16; r++) {
      const int q = (r & 3) + 8 * (r >> 2) + 4 * lh;
      aout[(row0 + q) * 2048 + h * 256 + ci * 32 + l31] = f2bf(acc[ci][r]);
    }
  }
}

extern "C" void kernel_launch(void* const* d_in, const int* in_sizes, int n_in,
                              void* d_out, int out_size, void* d_ws, size_t ws_size,
                              hipStream_t stream) {
  (void)in_sizes; (void)n_in; (void)out_size; (void)ws_size;
  const float* x      = (const float*)d_in[0];
  const float* t      = (const float*)d_in[1];
  const float* gamma  = (const float*)d_in[2];
  const float* beta   = (const float*)d_in[3];
  const float* pos    = (const float*)d_in[4];
  const float* Wqkv   = (const float*)d_in[5];
  const float* bqkv   = (const float*)d_in[6];
  const float* Wm     = (const float*)d_in[7];
  const float* bm     = (const float*)d_in[8];
  const float* Wt     = (const float*)d_in[9];
  const float* bt     = (const float*)d_in[10];
  const float* gamma1 = (const float*)d_in[11];
  const float* beta1  = (const float*)d_in[12];
  const float* Wf1    = (const float*)d_in[13];
  const float* bf1    = (const float*)d_in[14];
  const float* Wf2    = (const float*)d_in[15];
  const float* bf2    = (const float*)d_in[16];
  const float* scale  = (const float*)d_in[17];
  float* out = (float*)d_out;

  char* ws = (char*)d_ws;
  size_t off = 0;
  auto alloc = [&](size_t bytes) -> void* {
    void* p = ws + off;
    off += (bytes + 255) & ~(size_t)255;
    return p;
  };
  unsigned short* qkb   = (unsigned short*)alloc((size_t)8192 * 1024 * 2);
  unsigned short* vtb   = (unsigned short*)alloc((size_t)64 * 256 * 1024 * 2);
  unsigned short* aoutb = (unsigned short*)alloc((size_t)8192 * 2048 * 2);
  unsigned short* hbuf  = (unsigned short*)alloc((size_t)8192 * 256 * 2);
  unsigned short* ffbuf = (unsigned short*)alloc((size_t)8192 * 1024 * 2);
  float* x1             = (float*)alloc((size_t)8192 * 256 * 4);
  unsigned short* WqkvT = (unsigned short*)alloc((size_t)3072 * 256 * 2);
  unsigned short* WmT   = (unsigned short*)alloc((size_t)256 * 2048 * 2);
  unsigned short* Wf1T  = (unsigned short*)alloc((size_t)1024 * 256 * 2);
  unsigned short* Wf2T  = (unsigned short*)alloc((size_t)256 * 1024 * 2);
  float* partial = (float*)alloc((size_t)8 * 32 * 2 * 256 * 4);
  float* mean1   = (float*)alloc(8 * 256 * 4);
  float* rstd1   = (float*)alloc(8 * 256 * 4);
  float* mean2   = (float*)alloc(8 * 256 * 4);
  float* rstd2   = (float*)alloc(8 * 256 * 4);
  float* sig_ts  = (float*)alloc(8 * 1024 * 4);
  float* q2g     = (float*)alloc((size_t)64 * 1024 * 4);
  float* k2g     = (float*)alloc((size_t)64 * 1024 * 4);

  transpose4<<<2080, 256, 0, stream>>>(Wqkv, WqkvT, Wm, WmT, Wf1, Wf1T, Wf2, Wf2T,
                                       t, Wt, bt, sig_ts, x, partial);

  stats_pass2<<<8, 256, 0, stream>>>(partial, mean1, rstd1);
  norm_swish<true><<<2048, 256, 0, stream>>>(x, mean1, rstd1, gamma, beta, pos, hbuf);

  gemm2<0, 128><<<dim3(24, 64), 256, 0, stream>>>(hbuf, WqkvT, bqkv, nullptr, nullptr,
                                                  qkb, nullptr, vtb, 256, 3072, q2g, k2g);
  attn3<<<256, 512, 0, stream>>>(qkb, vtb, q2g, k2g, aoutb, scale);
  // Wm GEMM: EPI 3 writes x1 AND the seq-stats partials (deletes stats_pass1(x1))
  gemm2<3, 32><<<dim3(8, 64), 256, 0, stream>>>(aoutb, WmT, bm, x, nullptr,
                                                nullptr, x1, nullptr, 2048, 256,
                                                partial, nullptr);

  stats_pass2<<<8, 256, 0, stream>>>(partial, mean2, rstd2);
  norm_swish<false><<<2048, 256, 0, stream>>>(x1, mean2, rstd2, gamma1, beta1, nullptr, hbuf);

  gemm2<2, 128><<<dim3(8, 64), 256, 0, stream>>>(hbuf, Wf1T, bf1, nullptr, sig_ts,
                                                 ffbuf, nullptr, nullptr, 256, 1024,
                                                 nullptr, nullptr);
  gemm2<1, 32><<<dim3(8, 64), 256, 0, stream>>>(ffbuf, Wf2T, bf2, x1, nullptr,
                                                nullptr, out, nullptr, 1024, 256,
                                                nullptr, nullptr);
}